// Round 2
// baseline (180.678 us; speedup 1.0000x reference)
//
#include <hip/hip_runtime.h>
#include <stdint.h>

typedef _Float16 half8  __attribute__((ext_vector_type(8)));
typedef float    f32x4  __attribute__((ext_vector_type(4)));
typedef uint32_t u32x4  __attribute__((ext_vector_type(4)));

#define FIN  288
#define NOUT 64
#define LPB  3844            // 62*62
#define KSPL 72
#define NBF  20736           // bfrag half8 slots (331,776 B)
#define NBAS (16*64*32*64)   // basis half8 slots (33.5 MB), layout [b][h][cperm][w]
#define NXR  (16*64*64*4)    // relu(x) f16 slots, layout [b][h][w][quad] (4.2 MB)
#define PADS 16              // OOB-read pad (wo+jj can run 2 past row end)

// legacy LDS (fallback path, byte-identical to the round-0 verified kernel)
#define SCL  200
#define LDSL (31*SCL + 2*64 + 64 + 8)

// K-order (spline): kt = ii*24 + jj*8 + g, quad q -> channel c = 4g+q,
// feature f = 9c + 3ii + jj.  cperm = q*8 + g, so the A-fragment for
// (ii,jj,g) is ONE dwordx4 from bas[(b,ho+ii,q*8+g,w)].
// K-order (base): k8 = q*8+j -> feature f = 9*k8 + (3*i2+j2); A-fragment is
// ONE dwordx4 from xr16[(b,ho+i2,w+j2,q)] (8 consecutive channels, relu'd).

// ---------------- cubic B-spline basis: 8 slots, f16-packed ----------------
__device__ inline half8 bspline8(float xv) {
  float u = fmaf(xv, 2.5f, 5.5f);
  float fi = floorf(u);
  int i = (int)fi;
  float t = u - fi, s = 1.0f - t;
  float t2 = t * t, t3 = t2 * t;
  float s2 = s * s, s3 = s2 * s;
  float w3 = t3 * 0.16666667f;
  float w0 = s3 * 0.16666667f;
  float w1 = fmaf(0.5f, t3, -t2) + 0.66666667f;
  float w2 = fmaf(0.5f, s3, -s2) + 0.66666667f;
  uint32_t u01 = __builtin_bit_cast(uint32_t, __builtin_amdgcn_cvt_pkrtz(w0, w1));
  uint32_t u23 = __builtin_bit_cast(uint32_t, __builtin_amdgcn_cvt_pkrtz(w2, w3));
  uint64_t V = (uint64_t)u01 | ((uint64_t)u23 << 32);
  uint32_t vl = (uint32_t)(V << 16);
  u32x4 fr;
#pragma unroll
  for (int q = 0; q < 4; ++q) {
    int d = i - 2 * q;
    uint32_t rr = (uint32_t)(V >> ((48 - 16 * d) & 63));
    fr[q] = ((uint32_t)d <= 3u) ? rr : ((d == 4) ? vl : 0u);
  }
  return __builtin_bit_cast(half8, fr);
}

// -------- prep: basis + relu(x) f16 + weight B-fragments, all in ws --------
__global__ __launch_bounds__(256) void prep_all(const float* __restrict__ x,
                                                const float* __restrict__ bw,
                                                const float* __restrict__ sw,
                                                const float* __restrict__ sc,
                                                half8* __restrict__ ws) {
  int bid = blockIdx.x;
  if (bid < 2048) {
    // basis: thread handles 4 consecutive w of one (b,h,cperm) row
    int t = bid * 256 + threadIdx.x;        // 0..524287
    int w4 = t & 15;
    int cperm = (t >> 4) & 31;
    int bh = t >> 9;                        // b*64 + h
    int c = ((cperm & 7) << 2) | (cperm >> 3);   // c = 4g + quad
    const float4 v = *(const float4*)(x + (bh >> 6) * 131072 + c * 4096 +
                                      (bh & 63) * 64 + w4 * 4);
    half8* dst = ws + NBF + (size_t)t * 4;
    dst[0] = bspline8(v.x);
    dst[1] = bspline8(v.y);
    dst[2] = bspline8(v.z);
    dst[3] = bspline8(v.w);
  } else if (bid < 3072) {
    // relu(x) -> f16, channel-major: slot ((b*64+h)*64+w)*4 + quad
    int t = (bid - 2048) * 256 + threadIdx.x;    // 0..262143
    int quad = t & 3;
    int w = (t >> 2) & 63;
    int bh = t >> 8;                             // b*64 + h
    const float* xp = x + (bh >> 6) * 131072 + (quad * 8) * 4096 + (bh & 63) * 64 + w;
    half8 v;
#pragma unroll
    for (int j = 0; j < 8; ++j) v[j] = (_Float16)fmaxf(xp[j * 4096], 0.0f);
    ws[NBF + NBAS + t] = v;
  } else {
    int t = (bid - 3072) * 256 + threadIdx.x;    // 0..20735
    half8 v;
    int dst;
    if (t < NOUT * FIN) {                   // spline (o,f) pairs
      int o = t / FIN;
      int f = t - o * FIN;
      float scale = sc[t];
      const float* p = sw + t * 8;
#pragma unroll
      for (int c = 0; c < 8; ++c) v[c] = (_Float16)(p[c] * scale);
      int ch = f / 9;
      int r  = f - ch * 9;
      int ii = r / 3;
      int jj = r - ii * 3;
      int g  = ch >> 2, q = ch & 3;
      int kt = ii * 24 + jj * 8 + g;
      dst = (kt * 4 + (o >> 4)) * 64 + q * 16 + (o & 15);
    } else {                                // base frags, K-permuted
      int t2 = t - NOUT * FIN;
      int lane = t2 & 63;
      int nf = (t2 >> 6) & 3;
      int ktb = t2 >> 8;                    // 0..8
      int o = nf * 16 + (lane & 15);
      int q = lane >> 4;
      int i2 = ktb / 3;
      int j2 = ktb - 3 * i2;
#pragma unroll
      for (int c0 = 0; c0 < 8; ++c0)
        v[c0] = (_Float16)bw[o * FIN + 9 * (q * 8 + c0) + 3 * i2 + j2];
      dst = ((KSPL + ktb) * 4 + nf) * 64 + lane;
    }
    ws[dst] = v;
  }
}

// -------- main: M=64 px/wave, 4 ho rows/block, no LDS, no barriers --------
__global__ __launch_bounds__(256, 1) void kan_main(
    const half8* __restrict__ ws,
    float* __restrict__ out) {
  const half8* __restrict__ bfrag = ws;
  const half8* __restrict__ bas   = ws + NBF;
  const half8* __restrict__ xr    = ws + NBF + NBAS;

  const int tid = threadIdx.x;
  int bid0 = blockIdx.x;                // 0..255
  // XCD swizzle: 256 = 8*32, bijective; each XCD covers 2 full batches
  int bid = (bid0 & 7) * 32 + (bid0 >> 3);
  const int b  = bid >> 4;
  const int hg = bid & 15;

  const int lane = tid & 63;
  const int wv   = tid >> 6;
  const int quad = lane >> 4;
  const int m16  = lane & 15;
  const int ho   = hg * 4 + wv;         // 0..63; >=62 computes garbage, not stored
  const int hoc  = ho < 61 ? ho : 61;

  f32x4 acc[4][4];
#pragma unroll
  for (int mt = 0; mt < 4; ++mt)
#pragma unroll
    for (int nf = 0; nf < 4; ++nf) acc[mt][nf] = (f32x4){0.f, 0.f, 0.f, 0.f};

  // ---- spline K-slices ----
  const half8* bb = bas + ((b * 64 + hoc) * 32 + quad * 8) * 64 + m16;
  for (int ii = 0; ii < 3; ++ii) {
    for (int jj = 0; jj < 3; ++jj) {
      const half8* p   = bb + ii * 2048 + jj;
      const half8* bfp = bfrag + (ii * 24 + jj * 8) * 256 + lane;
#pragma unroll
      for (int g = 0; g < 8; ++g) {
        half8 af[4];
#pragma unroll
        for (int mt = 0; mt < 4; ++mt) af[mt] = p[g * 64 + mt * 16];
#pragma unroll
        for (int nf = 0; nf < 4; ++nf) {
          half8 bf = bfp[g * 256 + nf * 64];
#pragma unroll
          for (int mt = 0; mt < 4; ++mt)
            acc[mt][nf] = __builtin_amdgcn_mfma_f32_16x16x32_f16(af[mt], bf, acc[mt][nf], 0, 0, 0);
        }
      }
    }
  }

  // ---- base K-slices: A from relu'd channel-major f16 ----
  for (int kb = 0; kb < 9; ++kb) {
    int i2 = (kb * 11) >> 5;            // kb/3
    int j2 = kb - 3 * i2;
    const half8* q = xr + ((b * 64 + hoc + i2) * 64 + m16 + j2) * 4 + quad;
    half8 af[4];
#pragma unroll
    for (int mt = 0; mt < 4; ++mt) af[mt] = q[mt * 64];
    const half8* bfp = bfrag + (KSPL + kb) * 256 + lane;
#pragma unroll
    for (int nf = 0; nf < 4; ++nf) {
      half8 bf = bfp[nf * 64];
#pragma unroll
      for (int mt = 0; mt < 4; ++mt)
        acc[mt][nf] = __builtin_amdgcn_mfma_f32_16x16x32_f16(af[mt], bf, acc[mt][nf], 0, 0, 0);
    }
  }

  // ---- epilogue: col(=out)=m16, row(=pixel)=mt*16+quad*4+rg ----
  if (ho < 62) {
    float* ob = out + b * (NOUT * LPB) + ho * 62;
#pragma unroll
    for (int mt = 0; mt < 4; ++mt) {
#pragma unroll
      for (int rg = 0; rg < 4; ++rg) {
        int wo2 = mt * 16 + quad * 4 + rg;
        if (wo2 < 62) {
#pragma unroll
          for (int nf = 0; nf < 4; ++nf) {
            int o = nf * 16 + m16;
            ob[o * LPB + wo2] = acc[mt][nf][rg];
          }
        }
      }
    }
  }
}

// ================= legacy fallback (round-0 verified, verbatim) =================
__global__ void prep_bfrag_legacy(const float* __restrict__ bw,
                                  const float* __restrict__ sw,
                                  const float* __restrict__ sc,
                                  half8* __restrict__ bfrag) {
  int t = blockIdx.x * 256 + threadIdx.x;
  half8 v;
  int dst;
  if (t < NOUT * FIN) {
    int o = t / FIN;
    int f = t - o * FIN;
    float scale = sc[t];
    const float* p = sw + t * 8;
#pragma unroll
    for (int c = 0; c < 8; ++c) v[c] = (_Float16)(p[c] * scale);
    int ch = f / 9;
    int r  = f - ch * 9;
    int ii = r / 3;
    int jj = r - ii * 3;
    int g  = ch >> 2, q = ch & 3;
    int kt = ii * 24 + jj * 8 + g;
    dst = (kt * 4 + (o >> 4)) * 64 + q * 16 + (o & 15);
  } else {
    int t2 = t - NOUT * FIN;
    int lane = t2 & 63;
    int nf = (t2 >> 6) & 3;
    int ktb = t2 >> 8;
    int o = nf * 16 + (lane & 15);
    int f0 = ktb * 32 + (lane >> 4) * 8;
    const float* p = bw + o * FIN + f0;
#pragma unroll
    for (int c = 0; c < 8; ++c) v[c] = (_Float16)p[c];
    dst = ((KSPL + ktb) * 4 + nf) * 64 + lane;
  }
  bfrag[dst] = v;
}

__global__ __launch_bounds__(256, 4) void kan_main_legacy(
    const float* __restrict__ x,
    const half8* __restrict__ bfrag,
    float* __restrict__ out) {
  __shared__ float lx[LDSL];
  const int tid = threadIdx.x;
  const int bid = blockIdx.x;
  const int b  = bid / 62;
  const int ho = bid - b * 62;
  const float* xb = x + b * 131072 + ho * 64;
#pragma unroll
  for (int r = 0; r < 6; ++r) {
    int gid = r * 256 + tid;
    int row = gid >> 4;
    int c   = (row * 683) >> 11;
    int ii  = row - c * 3;
    int colv = (gid & 15) * 4;
    const float4 v = *(const float4*)(xb + c * 4096 + ii * 64 + colv);
    *(float4*)(&lx[c * SCL + ii * 64 + colv]) = v;
  }
  __syncthreads();
  const int lane = tid & 63;
  const int wv   = tid >> 6;
  const int quad = lane >> 4;
  const int m16  = lane & 15;
  const int wo   = wv * 16 + m16;
  f32x4 acc[4];
#pragma unroll
  for (int nf = 0; nf < 4; ++nf) acc[nf] = (f32x4){0.f, 0.f, 0.f, 0.f};
  int kt = 0;
#pragma unroll
  for (int ii = 0; ii < 3; ++ii) {
#pragma unroll
    for (int jj = 0; jj < 3; ++jj) {
      const float* lbase = lx + quad * SCL + ii * 64 + wo + jj;
#pragma unroll
      for (int g = 0; g < 8; ++g) {
        float xv = lbase[g * (4 * SCL)];
        half8 af = bspline8(xv);
#pragma unroll
        for (int nf = 0; nf < 4; ++nf) {
          half8 bf = bfrag[(kt * 4 + nf) * 64 + lane];
          acc[nf] = __builtin_amdgcn_mfma_f32_16x16x32_f16(af, bf, acc[nf], 0, 0, 0);
        }
        ++kt;
      }
    }
  }
#pragma unroll
  for (int kb = 0; kb < 9; ++kb) {
    int f0 = kb * 32 + quad * 8;
    half8 a;
#pragma unroll
    for (int j = 0; j < 8; ++j) {
      int f = f0 + j;
      int c = (f * 57) >> 9;
      int r = f - c * 9;
      int i2 = (r * 11) >> 5;
      int j2 = r - i2 * 3;
      a[j] = (_Float16)fmaxf(lx[c * SCL + i2 * 64 + wo + j2], 0.0f);
    }
#pragma unroll
    for (int nf = 0; nf < 4; ++nf) {
      half8 bf = bfrag[((KSPL + kb) * 4 + nf) * 64 + lane];
      acc[nf] = __builtin_amdgcn_mfma_f32_16x16x32_f16(a, bf, acc[nf], 0, 0, 0);
    }
  }
  float* ob = out + b * (NOUT * LPB) + ho * 62;
#pragma unroll
  for (int rg = 0; rg < 4; ++rg) {
    int wo2 = wv * 16 + quad * 4 + rg;
    if (wo2 < 62) {
#pragma unroll
      for (int nf = 0; nf < 4; ++nf) {
        int o = nf * 16 + m16;
        ob[o * LPB + wo2] = acc[nf][rg];
      }
    }
  }
}

extern "C" void kernel_launch(void* const* d_in, const int* in_sizes, int n_in,
                              void* d_out, int out_size, void* d_ws, size_t ws_size,
                              hipStream_t stream) {
  const float* x  = (const float*)d_in[0];
  const float* bw = (const float*)d_in[1];  // (64, 288)
  const float* sw = (const float*)d_in[2];  // (64, 288, 8)
  const float* sc = (const float*)d_in[3];  // (64, 288)
  float* out = (float*)d_out;
  half8* ws = (half8*)d_ws;

  const size_t need = (size_t)(NBF + NBAS + NXR + PADS) * sizeof(half8);  // ~38.1 MB
  if (ws_size >= need) {
    prep_all<<<3153, 256, 0, stream>>>(x, bw, sw, sc, ws);
    kan_main<<<256, 256, 0, stream>>>(ws, out);
  } else {
    prep_bfrag_legacy<<<81, 256, 0, stream>>>(bw, sw, sc, ws);
    kan_main_legacy<<<16 * 62, 256, 0, stream>>>(x, ws, out);
  }
}

// Round 4
// 132.145 us; speedup vs baseline: 1.3673x; 1.3673x over previous
//
#include <hip/hip_runtime.h>
#include <stdint.h>

typedef _Float16 half8  __attribute__((ext_vector_type(8)));
typedef float    f32x4  __attribute__((ext_vector_type(4)));
typedef uint32_t u32x4  __attribute__((ext_vector_type(4)));

#define FIN  288
#define NOUT 64
#define LPB  3844            // 62*62
#define KSPL 72
#define NBF  20736           // bfrag half8 slots (331,776 B)
#define NBAS (16*64*32*64)   // basis half8 slots (33.5 MB), layout [b][h][cperm][w]
#define NXR  (16*64*64*4)    // relu(x) f16 slots, layout [b][h][w][quad] (4.2 MB)
#define PADS 16              // OOB-read pad (w+jj can run 2 past row end)

// legacy LDS (fallback path, byte-identical to the round-0 verified kernel)
#define SCL  200
#define LDSL (31*SCL + 2*64 + 64 + 8)

// K-order (spline): kt = ii*24 + jj*8 + g, quad q -> channel c = 4g+q,
// feature f = 9c + 3ii + jj.  cperm = q*8 + g, so the A-fragment for
// (ii,jj,g) is ONE dwordx4 from bas[(b,ho+ii,q*8+g,w)].
// K-order (base): k8 = q*8+j -> feature f = 9*k8 + (3*i2+j2); A-fragment is
// ONE dwordx4 from xr16[(b,ho+i2,w+j2,q)] (8 consecutive channels, relu'd).

// ---------------- cubic B-spline basis: 8 slots, f16-packed ----------------
__device__ inline half8 bspline8(float xv) {
  float u = fmaf(xv, 2.5f, 5.5f);
  float fi = floorf(u);
  int i = (int)fi;
  float t = u - fi, s = 1.0f - t;
  float t2 = t * t, t3 = t2 * t;
  float s2 = s * s, s3 = s2 * s;
  float w3 = t3 * 0.16666667f;
  float w0 = s3 * 0.16666667f;
  float w1 = fmaf(0.5f, t3, -t2) + 0.66666667f;
  float w2 = fmaf(0.5f, s3, -s2) + 0.66666667f;
  uint32_t u01 = __builtin_bit_cast(uint32_t, __builtin_amdgcn_cvt_pkrtz(w0, w1));
  uint32_t u23 = __builtin_bit_cast(uint32_t, __builtin_amdgcn_cvt_pkrtz(w2, w3));
  uint64_t V = (uint64_t)u01 | ((uint64_t)u23 << 32);
  uint32_t vl = (uint32_t)(V << 16);
  u32x4 fr;
#pragma unroll
  for (int q = 0; q < 4; ++q) {
    int d = i - 2 * q;
    uint32_t rr = (uint32_t)(V >> ((48 - 16 * d) & 63));
    fr[q] = ((uint32_t)d <= 3u) ? rr : ((d == 4) ? vl : 0u);
  }
  return __builtin_bit_cast(half8, fr);
}

// -------- prep: basis + relu(x) f16 + weight B-fragments, all in ws --------
__global__ __launch_bounds__(256) void prep_all(const float* __restrict__ x,
                                                const float* __restrict__ bw,
                                                const float* __restrict__ sw,
                                                const float* __restrict__ sc,
                                                half8* __restrict__ ws) {
  int bid = blockIdx.x;
  if (bid < 2048) {
    // basis: thread handles 4 consecutive w of one (b,h,cperm) row
    int t = bid * 256 + threadIdx.x;        // 0..524287
    int w4 = t & 15;
    int cperm = (t >> 4) & 31;
    int bh = t >> 9;                        // b*64 + h
    int c = ((cperm & 7) << 2) | (cperm >> 3);   // c = 4g + quad
    const float4 v = *(const float4*)(x + (bh >> 6) * 131072 + c * 4096 +
                                      (bh & 63) * 64 + w4 * 4);
    half8* dst = ws + NBF + (size_t)t * 4;
    dst[0] = bspline8(v.x);
    dst[1] = bspline8(v.y);
    dst[2] = bspline8(v.z);
    dst[3] = bspline8(v.w);
  } else if (bid < 3072) {
    // relu(x) -> f16, channel-major: slot ((b*64+h)*64+w)*4 + quad
    int t = (bid - 2048) * 256 + threadIdx.x;    // 0..262143
    int quad = t & 3;
    int w = (t >> 2) & 63;
    int bh = t >> 8;                             // b*64 + h
    const float* xp = x + (bh >> 6) * 131072 + (quad * 8) * 4096 + (bh & 63) * 64 + w;
    half8 v;
#pragma unroll
    for (int j = 0; j < 8; ++j) v[j] = (_Float16)fmaxf(xp[j * 4096], 0.0f);
    ws[NBF + NBAS + t] = v;
  } else {
    int t = (bid - 3072) * 256 + threadIdx.x;    // 0..20735
    half8 v;
    int dst;
    if (t < NOUT * FIN) {                   // spline (o,f) pairs
      int o = t / FIN;
      int f = t - o * FIN;
      float scale = sc[t];
      const float* p = sw + t * 8;
#pragma unroll
      for (int c = 0; c < 8; ++c) v[c] = (_Float16)(p[c] * scale);
      int ch = f / 9;
      int r  = f - ch * 9;
      int ii = r / 3;
      int jj = r - ii * 3;
      int g  = ch >> 2, q = ch & 3;
      int kt = ii * 24 + jj * 8 + g;
      dst = (kt * 4 + (o >> 4)) * 64 + q * 16 + (o & 15);
    } else {                                // base frags, K-permuted
      int t2 = t - NOUT * FIN;
      int lane = t2 & 63;
      int nf = (t2 >> 6) & 3;
      int ktb = t2 >> 8;                    // 0..8
      int o = nf * 16 + (lane & 15);
      int q = lane >> 4;
      int i2 = ktb / 3;
      int j2 = ktb - 3 * i2;
#pragma unroll
      for (int c0 = 0; c0 < 8; ++c0)
        v[c0] = (_Float16)bw[o * FIN + 9 * (q * 8 + c0) + 3 * i2 + j2];
      dst = ((KSPL + ktb) * 4 + nf) * 64 + lane;
    }
    ws[dst] = v;
  }
}

// ---- main: M=64 px/wave, N=32 outs/block (blockIdx.y half), no LDS ----
// Minimal diff from the round-2 verified kernel: nf loop 4->2 with nfb offset.
__global__ __launch_bounds__(256, 2) void kan_main(
    const half8* __restrict__ ws,
    float* __restrict__ out) {
  const half8* __restrict__ bfrag = ws;
  const half8* __restrict__ bas   = ws + NBF;
  const half8* __restrict__ xr    = ws + NBF + NBAS;

  const int tid = threadIdx.x;
  int bid0 = blockIdx.x;                // 0..255
  // XCD swizzle: 256 = 8*32, bijective
  int bid = (bid0 & 7) * 32 + (bid0 >> 3);
  const int b  = bid >> 4;
  const int hg = bid & 15;
  const int nfb = blockIdx.y * 2;       // output half: nf in {nfb, nfb+1}

  const int lane = tid & 63;
  const int wv   = tid >> 6;
  const int quad = lane >> 4;
  const int m16  = lane & 15;
  const int ho   = hg * 4 + wv;         // 0..63; >=62 computes garbage, not stored
  const int hoc  = ho < 61 ? ho : 61;

  f32x4 acc[4][2];
#pragma unroll
  for (int mt = 0; mt < 4; ++mt)
#pragma unroll
    for (int nf = 0; nf < 2; ++nf) acc[mt][nf] = (f32x4){0.f, 0.f, 0.f, 0.f};

  // ---- spline K-slices ----
  const half8* bb = bas + ((b * 64 + hoc) * 32 + quad * 8) * 64 + m16;
  for (int ii = 0; ii < 3; ++ii) {
    for (int jj = 0; jj < 3; ++jj) {
      const half8* p   = bb + ii * 2048 + jj;
      const half8* bfp = bfrag + (ii * 24 + jj * 8) * 256 + nfb * 64 + lane;
#pragma unroll
      for (int g = 0; g < 8; ++g) {
        half8 af[4];
#pragma unroll
        for (int mt = 0; mt < 4; ++mt) af[mt] = p[g * 64 + mt * 16];
#pragma unroll
        for (int nf = 0; nf < 2; ++nf) {
          half8 bf = bfp[g * 256 + nf * 64];
#pragma unroll
          for (int mt = 0; mt < 4; ++mt)
            acc[mt][nf] = __builtin_amdgcn_mfma_f32_16x16x32_f16(af[mt], bf, acc[mt][nf], 0, 0, 0);
        }
      }
    }
  }

  // ---- base K-slices: A from relu'd channel-major f16 ----
  for (int kb = 0; kb < 9; ++kb) {
    int i2 = (kb * 11) >> 5;            // kb/3
    int j2 = kb - 3 * i2;
    const half8* q = xr + ((b * 64 + hoc + i2) * 64 + m16 + j2) * 4 + quad;
    half8 af[4];
#pragma unroll
    for (int mt = 0; mt < 4; ++mt) af[mt] = q[mt * 64];
    const half8* bfp = bfrag + (KSPL + kb) * 256 + nfb * 64 + lane;
#pragma unroll
    for (int nf = 0; nf < 2; ++nf) {
      half8 bf = bfp[nf * 64];
#pragma unroll
      for (int mt = 0; mt < 4; ++mt)
        acc[mt][nf] = __builtin_amdgcn_mfma_f32_16x16x32_f16(af[mt], bf, acc[mt][nf], 0, 0, 0);
    }
  }

  // ---- epilogue: col(=out)=m16, row(=pixel)=mt*16+quad*4+rg ----
  if (ho < 62) {
    float* ob = out + b * (NOUT * LPB) + ho * 62;
#pragma unroll
    for (int mt = 0; mt < 4; ++mt) {
#pragma unroll
      for (int rg = 0; rg < 4; ++rg) {
        int wo2 = mt * 16 + quad * 4 + rg;
        if (wo2 < 62) {
#pragma unroll
          for (int nf = 0; nf < 2; ++nf) {
            int o = (nfb + nf) * 16 + m16;
            ob[o * LPB + wo2] = acc[mt][nf][rg];
          }
        }
      }
    }
  }
}

// ================= legacy fallback (round-0 verified, verbatim) =================
__global__ void prep_bfrag_legacy(const float* __restrict__ bw,
                                  const float* __restrict__ sw,
                                  const float* __restrict__ sc,
                                  half8* __restrict__ bfrag) {
  int t = blockIdx.x * 256 + threadIdx.x;
  half8 v;
  int dst;
  if (t < NOUT * FIN) {
    int o = t / FIN;
    int f = t - o * FIN;
    float scale = sc[t];
    const float* p = sw + t * 8;
#pragma unroll
    for (int c = 0; c < 8; ++c) v[c] = (_Float16)(p[c] * scale);
    int ch = f / 9;
    int r  = f - ch * 9;
    int ii = r / 3;
    int jj = r - ii * 3;
    int g  = ch >> 2, q = ch & 3;
    int kt = ii * 24 + jj * 8 + g;
    dst = (kt * 4 + (o >> 4)) * 64 + q * 16 + (o & 15);
  } else {
    int t2 = t - NOUT * FIN;
    int lane = t2 & 63;
    int nf = (t2 >> 6) & 3;
    int ktb = t2 >> 8;
    int o = nf * 16 + (lane & 15);
    int f0 = ktb * 32 + (lane >> 4) * 8;
    const float* p = bw + o * FIN + f0;
#pragma unroll
    for (int c = 0; c < 8; ++c) v[c] = (_Float16)p[c];
    dst = ((KSPL + ktb) * 4 + nf) * 64 + lane;
  }
  bfrag[dst] = v;
}

__global__ __launch_bounds__(256, 4) void kan_main_legacy(
    const float* __restrict__ x,
    const half8* __restrict__ bfrag,
    float* __restrict__ out) {
  __shared__ float lx[LDSL];
  const int tid = threadIdx.x;
  const int bid = blockIdx.x;
  const int b  = bid / 62;
  const int ho = bid - b * 62;
  const float* xb = x + b * 131072 + ho * 64;
#pragma unroll
  for (int r = 0; r < 6; ++r) {
    int gid = r * 256 + tid;
    int row = gid >> 4;
    int c   = (row * 683) >> 11;
    int ii  = row - c * 3;
    int colv = (gid & 15) * 4;
    const float4 v = *(const float4*)(xb + c * 4096 + ii * 64 + colv);
    *(float4*)(&lx[c * SCL + ii * 64 + colv]) = v;
  }
  __syncthreads();
  const int lane = tid & 63;
  const int wv   = tid >> 6;
  const int quad = lane >> 4;
  const int m16  = lane & 15;
  const int wo   = wv * 16 + m16;
  f32x4 acc[4];
#pragma unroll
  for (int nf = 0; nf < 4; ++nf) acc[nf] = (f32x4){0.f, 0.f, 0.f, 0.f};
  int kt = 0;
#pragma unroll
  for (int ii = 0; ii < 3; ++ii) {
#pragma unroll
    for (int jj = 0; jj < 3; ++jj) {
      const float* lbase = lx + quad * SCL + ii * 64 + wo + jj;
#pragma unroll
      for (int g = 0; g < 8; ++g) {
        float xv = lbase[g * (4 * SCL)];
        half8 af = bspline8(xv);
#pragma unroll
        for (int nf = 0; nf < 4; ++nf) {
          half8 bf = bfrag[(kt * 4 + nf) * 64 + lane];
          acc[nf] = __builtin_amdgcn_mfma_f32_16x16x32_f16(af, bf, acc[nf], 0, 0, 0);
        }
        ++kt;
      }
    }
  }
#pragma unroll
  for (int kb = 0; kb < 9; ++kb) {
    int f0 = kb * 32 + quad * 8;
    half8 a;
#pragma unroll
    for (int j = 0; j < 8; ++j) {
      int f = f0 + j;
      int c = (f * 57) >> 9;
      int r = f - c * 9;
      int i2 = (r * 11) >> 5;
      int j2 = r - i2 * 3;
      a[j] = (_Float16)fmaxf(lx[c * SCL + i2 * 64 + wo + j2], 0.0f);
    }
#pragma unroll
    for (int nf = 0; nf < 4; ++nf) {
      half8 bf = bfrag[((KSPL + kb) * 4 + nf) * 64 + lane];
      acc[nf] = __builtin_amdgcn_mfma_f32_16x16x32_f16(a, bf, acc[nf], 0, 0, 0);
    }
  }
  float* ob = out + b * (NOUT * LPB) + ho * 62;
#pragma unroll
  for (int rg = 0; rg < 4; ++rg) {
    int wo2 = wv * 16 + quad * 4 + rg;
    if (wo2 < 62) {
#pragma unroll
      for (int nf = 0; nf < 4; ++nf) {
        int o = nf * 16 + m16;
        ob[o * LPB + wo2] = acc[nf][rg];
      }
    }
  }
}

extern "C" void kernel_launch(void* const* d_in, const int* in_sizes, int n_in,
                              void* d_out, int out_size, void* d_ws, size_t ws_size,
                              hipStream_t stream) {
  const float* x  = (const float*)d_in[0];
  const float* bw = (const float*)d_in[1];  // (64, 288)
  const float* sw = (const float*)d_in[2];  // (64, 288, 8)
  const float* sc = (const float*)d_in[3];  // (64, 288)
  float* out = (float*)d_out;
  half8* ws = (half8*)d_ws;

  const size_t need = (size_t)(NBF + NBAS + NXR + PADS) * sizeof(half8);  // ~38.1 MB
  if (ws_size >= need) {
    prep_all<<<3153, 256, 0, stream>>>(x, bw, sw, sc, ws);
    kan_main<<<dim3(256, 2), 256, 0, stream>>>(ws, out);
  } else {
    prep_bfrag_legacy<<<81, 256, 0, stream>>>(bw, sw, sc, ws);
    kan_main_legacy<<<16 * 62, 256, 0, stream>>>(x, ws, out);
  }
}

// Round 5
// 130.162 us; speedup vs baseline: 1.3881x; 1.0152x over previous
//
#include <hip/hip_runtime.h>
#include <stdint.h>

typedef _Float16 half8  __attribute__((ext_vector_type(8)));
typedef float    f32x4  __attribute__((ext_vector_type(4)));
typedef uint32_t u32x4  __attribute__((ext_vector_type(4)));

#define FIN  288
#define NOUT 64
#define LPB  3844            // 62*62
#define KSPL 72
#define NBF  20736           // bfrag half8 slots (331,776 B)
#define NBAS (16*64*32*64)   // basis half8 slots (33.5 MB), layout [b][h][cperm][w]
#define NXR  (16*64*64*4)    // relu(x) f16 slots, layout [b][h][w][quad] (4.2 MB)
#define PADS 16              // OOB-read pad (w+jj can run 2 past row end)

// legacy LDS (fallback path, byte-identical to the round-0 verified kernel)
#define SCL  200
#define LDSL (31*SCL + 2*64 + 64 + 8)

// K-order (spline): kt = ii*24 + jj*8 + g, quad q -> channel c = 4g+q,
// feature f = 9c + 3ii + jj.  cperm = q*8 + g, so the A-fragment for
// (ii,jj,g) is ONE dwordx4 from bas[(b,ho+ii,q*8+g,w)].
// K-order (base): k8 = q*8+j -> feature f = 9*k8 + (3*i2+j2); A-fragment is
// ONE dwordx4 from xr16[(b,ho+i2,w+j2,q)] (8 consecutive channels, relu'd).

// ---------------- cubic B-spline basis: 8 slots, f16-packed ----------------
__device__ inline half8 bspline8(float xv) {
  float u = fmaf(xv, 2.5f, 5.5f);
  float fi = floorf(u);
  int i = (int)fi;
  float t = u - fi, s = 1.0f - t;
  float t2 = t * t, t3 = t2 * t;
  float s2 = s * s, s3 = s2 * s;
  float w3 = t3 * 0.16666667f;
  float w0 = s3 * 0.16666667f;
  float w1 = fmaf(0.5f, t3, -t2) + 0.66666667f;
  float w2 = fmaf(0.5f, s3, -s2) + 0.66666667f;
  uint32_t u01 = __builtin_bit_cast(uint32_t, __builtin_amdgcn_cvt_pkrtz(w0, w1));
  uint32_t u23 = __builtin_bit_cast(uint32_t, __builtin_amdgcn_cvt_pkrtz(w2, w3));
  uint64_t V = (uint64_t)u01 | ((uint64_t)u23 << 32);
  uint32_t vl = (uint32_t)(V << 16);
  u32x4 fr;
#pragma unroll
  for (int q = 0; q < 4; ++q) {
    int d = i - 2 * q;
    uint32_t rr = (uint32_t)(V >> ((48 - 16 * d) & 63));
    fr[q] = ((uint32_t)d <= 3u) ? rr : ((d == 4) ? vl : 0u);
  }
  return __builtin_bit_cast(half8, fr);
}

// -------- prep: basis + relu(x) f16 + weight B-fragments, all in ws --------
__global__ __launch_bounds__(256) void prep_all(const float* __restrict__ x,
                                                const float* __restrict__ bw,
                                                const float* __restrict__ sw,
                                                const float* __restrict__ sc,
                                                half8* __restrict__ ws) {
  int bid = blockIdx.x;
  if (bid < 2048) {
    // basis: thread handles 4 consecutive w of one (b,h,cperm) row
    int t = bid * 256 + threadIdx.x;        // 0..524287
    int w4 = t & 15;
    int cperm = (t >> 4) & 31;
    int bh = t >> 9;                        // b*64 + h
    int c = ((cperm & 7) << 2) | (cperm >> 3);   // c = 4g + quad
    const float4 v = *(const float4*)(x + (bh >> 6) * 131072 + c * 4096 +
                                      (bh & 63) * 64 + w4 * 4);
    half8* dst = ws + NBF + (size_t)t * 4;
    dst[0] = bspline8(v.x);
    dst[1] = bspline8(v.y);
    dst[2] = bspline8(v.z);
    dst[3] = bspline8(v.w);
  } else if (bid < 3072) {
    // relu(x) -> f16, channel-major: slot ((b*64+h)*64+w)*4 + quad
    int t = (bid - 2048) * 256 + threadIdx.x;    // 0..262143
    int quad = t & 3;
    int w = (t >> 2) & 63;
    int bh = t >> 8;                             // b*64 + h
    const float* xp = x + (bh >> 6) * 131072 + (quad * 8) * 4096 + (bh & 63) * 64 + w;
    half8 v;
#pragma unroll
    for (int j = 0; j < 8; ++j) v[j] = (_Float16)fmaxf(xp[j * 4096], 0.0f);
    ws[NBF + NBAS + t] = v;
  } else {
    int t = (bid - 3072) * 256 + threadIdx.x;    // 0..20735
    half8 v;
    int dst;
    if (t < NOUT * FIN) {                   // spline (o,f) pairs
      int o = t / FIN;
      int f = t - o * FIN;
      float scale = sc[t];
      const float* p = sw + t * 8;
#pragma unroll
      for (int c = 0; c < 8; ++c) v[c] = (_Float16)(p[c] * scale);
      int ch = f / 9;
      int r  = f - ch * 9;
      int ii = r / 3;
      int jj = r - ii * 3;
      int g  = ch >> 2, q = ch & 3;
      int kt = ii * 24 + jj * 8 + g;
      dst = (kt * 4 + (o >> 4)) * 64 + q * 16 + (o & 15);
    } else {                                // base frags, K-permuted
      int t2 = t - NOUT * FIN;
      int lane = t2 & 63;
      int nf = (t2 >> 6) & 3;
      int ktb = t2 >> 8;                    // 0..8
      int o = nf * 16 + (lane & 15);
      int q = lane >> 4;
      int i2 = ktb / 3;
      int j2 = ktb - 3 * i2;
#pragma unroll
      for (int c0 = 0; c0 < 8; ++c0)
        v[c0] = (_Float16)bw[o * FIN + 9 * (q * 8 + c0) + 3 * i2 + j2];
      dst = ((KSPL + ktb) * 4 + nf) * 64 + lane;
    }
    ws[dst] = v;
  }
}

// ---- main: M=64 px/wave, N=32/block (blockIdx.y), in-block K-split ----
// 8 waves: group 0 (wv<4) = spline pairs 0..4; group 1 = pairs 5..8 + base.
// Group 1 partials reduced into group 0 via LDS. Inner code identical to the
// round-4 verified kernel; only slice ranges are parametrized (wave-uniform).
#define REDSTR 36   // floats per lane slot (16B aligned, rotates banks by 4)
__global__ __launch_bounds__(512, 4) void kan_main(
    const half8* __restrict__ ws,
    float* __restrict__ out) {
  __shared__ float red[4 * 64 * REDSTR];   // 36 KB
  const half8* __restrict__ bfrag = ws;
  const half8* __restrict__ bas   = ws + NBF;
  const half8* __restrict__ xr    = ws + NBF + NBAS;

  const int tid = threadIdx.x;
  int bid0 = blockIdx.x;                // 0..255
  // XCD swizzle: 256 = 8*32, bijective
  int bid = (bid0 & 7) * 32 + (bid0 >> 3);
  const int b  = bid >> 4;
  const int hg = bid & 15;
  const int nfb = blockIdx.y * 2;       // output half: nf in {nfb, nfb+1}

  const int lane = tid & 63;
  const int wv   = tid >> 6;            // 0..7
  const int g2   = wv >> 2;             // K-group
  const int rw   = wv & 3;              // row-wave within group
  const int quad = lane >> 4;
  const int m16  = lane & 15;
  const int ho   = hg * 4 + rw;         // 0..63; >=62 computes garbage, not stored
  const int hoc  = ho < 61 ? ho : 61;

  f32x4 acc[4][2];
#pragma unroll
  for (int mt = 0; mt < 4; ++mt)
#pragma unroll
    for (int nf = 0; nf < 2; ++nf) acc[mt][nf] = (f32x4){0.f, 0.f, 0.f, 0.f};

  // ---- spline K-slices: pairs [plo,phi) of (ii,jj) ----
  const half8* bb = bas + ((b * 64 + hoc) * 32 + quad * 8) * 64 + m16;
  const int plo = g2 ? 5 : 0;
  const int phi = g2 ? 9 : 5;
  for (int pp = plo; pp < phi; ++pp) {
    int ii = (pp * 11) >> 5;            // pp/3 for pp<9
    int jj = pp - 3 * ii;
    const half8* p   = bb + ii * 2048 + jj;
    const half8* bfp = bfrag + (pp * 8) * 256 + nfb * 64 + lane;
#pragma unroll
    for (int g = 0; g < 8; ++g) {
      half8 af[4];
#pragma unroll
      for (int mt = 0; mt < 4; ++mt) af[mt] = p[g * 64 + mt * 16];
#pragma unroll
      for (int nf = 0; nf < 2; ++nf) {
        half8 bf = bfp[g * 256 + nf * 64];
#pragma unroll
        for (int mt = 0; mt < 4; ++mt)
          acc[mt][nf] = __builtin_amdgcn_mfma_f32_16x16x32_f16(af[mt], bf, acc[mt][nf], 0, 0, 0);
      }
    }
  }

  // ---- base K-slices (group 1 only) ----
  if (g2) {
    for (int kb = 0; kb < 9; ++kb) {
      int i2 = (kb * 11) >> 5;          // kb/3
      int j2 = kb - 3 * i2;
      const half8* q = xr + ((b * 64 + hoc + i2) * 64 + m16 + j2) * 4 + quad;
      half8 af[4];
#pragma unroll
      for (int mt = 0; mt < 4; ++mt) af[mt] = q[mt * 64];
      const half8* bfp = bfrag + (KSPL + kb) * 256 + nfb * 64 + lane;
#pragma unroll
      for (int nf = 0; nf < 2; ++nf) {
        half8 bf = bfp[nf * 64];
#pragma unroll
        for (int mt = 0; mt < 4; ++mt)
          acc[mt][nf] = __builtin_amdgcn_mfma_f32_16x16x32_f16(af[mt], bf, acc[mt][nf], 0, 0, 0);
      }
    }
    // dump partials
    int base = (rw * 64 + lane) * REDSTR;
#pragma unroll
    for (int mt = 0; mt < 4; ++mt)
#pragma unroll
      for (int nf = 0; nf < 2; ++nf)
        *(f32x4*)&red[base + (mt * 2 + nf) * 4] = acc[mt][nf];
  }

  __syncthreads();

  // ---- group 0: reduce + store. col(=out)=m16, row(=pixel)=mt*16+quad*4+rg ----
  if (!g2) {
    int base = (rw * 64 + lane) * REDSTR;
#pragma unroll
    for (int mt = 0; mt < 4; ++mt)
#pragma unroll
      for (int nf = 0; nf < 2; ++nf)
        acc[mt][nf] += *(const f32x4*)&red[base + (mt * 2 + nf) * 4];

    if (ho < 62) {
      float* ob = out + b * (NOUT * LPB) + ho * 62;
#pragma unroll
      for (int mt = 0; mt < 4; ++mt) {
#pragma unroll
        for (int rg = 0; rg < 4; ++rg) {
          int wo2 = mt * 16 + quad * 4 + rg;
          if (wo2 < 62) {
#pragma unroll
            for (int nf = 0; nf < 2; ++nf) {
              int o = (nfb + nf) * 16 + m16;
              ob[o * LPB + wo2] = acc[mt][nf][rg];
            }
          }
        }
      }
    }
  }
}

// ================= legacy fallback (round-0 verified, verbatim) =================
__global__ void prep_bfrag_legacy(const float* __restrict__ bw,
                                  const float* __restrict__ sw,
                                  const float* __restrict__ sc,
                                  half8* __restrict__ bfrag) {
  int t = blockIdx.x * 256 + threadIdx.x;
  half8 v;
  int dst;
  if (t < NOUT * FIN) {
    int o = t / FIN;
    int f = t - o * FIN;
    float scale = sc[t];
    const float* p = sw + t * 8;
#pragma unroll
    for (int c = 0; c < 8; ++c) v[c] = (_Float16)(p[c] * scale);
    int ch = f / 9;
    int r  = f - ch * 9;
    int ii = r / 3;
    int jj = r - ii * 3;
    int g  = ch >> 2, q = ch & 3;
    int kt = ii * 24 + jj * 8 + g;
    dst = (kt * 4 + (o >> 4)) * 64 + q * 16 + (o & 15);
  } else {
    int t2 = t - NOUT * FIN;
    int lane = t2 & 63;
    int nf = (t2 >> 6) & 3;
    int ktb = t2 >> 8;
    int o = nf * 16 + (lane & 15);
    int f0 = ktb * 32 + (lane >> 4) * 8;
    const float* p = bw + o * FIN + f0;
#pragma unroll
    for (int c = 0; c < 8; ++c) v[c] = (_Float16)p[c];
    dst = ((KSPL + ktb) * 4 + nf) * 64 + lane;
  }
  bfrag[dst] = v;
}

__global__ __launch_bounds__(256, 4) void kan_main_legacy(
    const float* __restrict__ x,
    const half8* __restrict__ bfrag,
    float* __restrict__ out) {
  __shared__ float lx[LDSL];
  const int tid = threadIdx.x;
  const int bid = blockIdx.x;
  const int b  = bid / 62;
  const int ho = bid - b * 62;
  const float* xb = x + b * 131072 + ho * 64;
#pragma unroll
  for (int r = 0; r < 6; ++r) {
    int gid = r * 256 + tid;
    int row = gid >> 4;
    int c   = (row * 683) >> 11;
    int ii  = row - c * 3;
    int colv = (gid & 15) * 4;
    const float4 v = *(const float4*)(xb + c * 4096 + ii * 64 + colv);
    *(float4*)(&lx[c * SCL + ii * 64 + colv]) = v;
  }
  __syncthreads();
  const int lane = tid & 63;
  const int wv   = tid >> 6;
  const int quad = lane >> 4;
  const int m16  = lane & 15;
  const int wo   = wv * 16 + m16;
  f32x4 acc[4];
#pragma unroll
  for (int nf = 0; nf < 4; ++nf) acc[nf] = (f32x4){0.f, 0.f, 0.f, 0.f};
  int kt = 0;
#pragma unroll
  for (int ii = 0; ii < 3; ++ii) {
#pragma unroll
    for (int jj = 0; jj < 3; ++jj) {
      const float* lbase = lx + quad * SCL + ii * 64 + wo + jj;
#pragma unroll
      for (int g = 0; g < 8; ++g) {
        float xv = lbase[g * (4 * SCL)];
        half8 af = bspline8(xv);
#pragma unroll
        for (int nf = 0; nf < 4; ++nf) {
          half8 bf = bfrag[(kt * 4 + nf) * 64 + lane];
          acc[nf] = __builtin_amdgcn_mfma_f32_16x16x32_f16(af, bf, acc[nf], 0, 0, 0);
        }
        ++kt;
      }
    }
  }
#pragma unroll
  for (int kb = 0; kb < 9; ++kb) {
    int f0 = kb * 32 + quad * 8;
    half8 a;
#pragma unroll
    for (int j = 0; j < 8; ++j) {
      int f = f0 + j;
      int c = (f * 57) >> 9;
      int r = f - c * 9;
      int i2 = (r * 11) >> 5;
      int j2 = r - i2 * 3;
      a[j] = (_Float16)fmaxf(lx[c * SCL + i2 * 64 + wo + j2], 0.0f);
    }
#pragma unroll
    for (int nf = 0; nf < 4; ++nf) {
      half8 bf = bfrag[((KSPL + kb) * 4 + nf) * 64 + lane];
      acc[nf] = __builtin_amdgcn_mfma_f32_16x16x32_f16(a, bf, acc[nf], 0, 0, 0);
    }
  }
  float* ob = out + b * (NOUT * LPB) + ho * 62;
#pragma unroll
  for (int rg = 0; rg < 4; ++rg) {
    int wo2 = wv * 16 + quad * 4 + rg;
    if (wo2 < 62) {
#pragma unroll
      for (int nf = 0; nf < 4; ++nf) {
        int o = nf * 16 + m16;
        ob[o * LPB + wo2] = acc[nf][rg];
      }
    }
  }
}

extern "C" void kernel_launch(void* const* d_in, const int* in_sizes, int n_in,
                              void* d_out, int out_size, void* d_ws, size_t ws_size,
                              hipStream_t stream) {
  const float* x  = (const float*)d_in[0];
  const float* bw = (const float*)d_in[1];  // (64, 288)
  const float* sw = (const float*)d_in[2];  // (64, 288, 8)
  const float* sc = (const float*)d_in[3];  // (64, 288)
  float* out = (float*)d_out;
  half8* ws = (half8*)d_ws;

  const size_t need = (size_t)(NBF + NBAS + NXR + PADS) * sizeof(half8);  // ~38.1 MB
  if (ws_size >= need) {
    prep_all<<<3153, 256, 0, stream>>>(x, bw, sw, sc, ws);
    kan_main<<<dim3(256, 2), 512, 0, stream>>>(ws, out);
  } else {
    prep_bfrag_legacy<<<81, 256, 0, stream>>>(bw, sw, sc, ws);
    kan_main_legacy<<<16 * 62, 256, 0, stream>>>(x, ws, out);
  }
}

// Round 6
// 121.986 us; speedup vs baseline: 1.4811x; 1.0670x over previous
//
#include <hip/hip_runtime.h>
#include <stdint.h>

typedef _Float16 half8  __attribute__((ext_vector_type(8)));
typedef float    f32x4  __attribute__((ext_vector_type(4)));
typedef uint32_t u32x4  __attribute__((ext_vector_type(4)));

#define FIN  288
#define NOUT 64
#define LPB  3844            // 62*62
#define KSPL 72
#define NBF  20736           // bfrag half8 slots (331,776 B)
#define NBAS (16*64*32*64)   // basis half8 slots (33.5 MB), layout [b][h][cperm][w]
#define NXR  (16*64*64*4)    // relu(x) f16 slots, layout [b][h][w][quad] (4.2 MB)
#define PADS 16              // OOB-read pad (w+jj can run 2 past row end)

// legacy LDS (fallback path, byte-identical to the round-0 verified kernel)
#define SCL  200
#define LDSL (31*SCL + 2*64 + 64 + 8)

// K-order (spline): kt = ii*24 + jj*8 + g, quad q -> channel c = 4g+q,
// feature f = 9c + 3ii + jj.  cperm = q*8 + g, so the A-fragment for
// (ii,jj,g) is ONE dwordx4 from bas[(b,ho+ii,q*8+g,w)].
// K-order (base): k8 = q*8+j -> feature f = 9*k8 + (3*i2+j2); A-fragment is
// ONE dwordx4 from xr16[(b,ho+i2,w+j2,q)] (8 consecutive channels, relu'd).

// ---------------- cubic B-spline basis: 8 slots, f16-packed ----------------
__device__ inline half8 bspline8(float xv) {
  float u = fmaf(xv, 2.5f, 5.5f);
  float fi = floorf(u);
  int i = (int)fi;
  float t = u - fi, s = 1.0f - t;
  float t2 = t * t, t3 = t2 * t;
  float s2 = s * s, s3 = s2 * s;
  float w3 = t3 * 0.16666667f;
  float w0 = s3 * 0.16666667f;
  float w1 = fmaf(0.5f, t3, -t2) + 0.66666667f;
  float w2 = fmaf(0.5f, s3, -s2) + 0.66666667f;
  uint32_t u01 = __builtin_bit_cast(uint32_t, __builtin_amdgcn_cvt_pkrtz(w0, w1));
  uint32_t u23 = __builtin_bit_cast(uint32_t, __builtin_amdgcn_cvt_pkrtz(w2, w3));
  uint64_t V = (uint64_t)u01 | ((uint64_t)u23 << 32);
  uint32_t vl = (uint32_t)(V << 16);
  u32x4 fr;
#pragma unroll
  for (int q = 0; q < 4; ++q) {
    int d = i - 2 * q;
    uint32_t rr = (uint32_t)(V >> ((48 - 16 * d) & 63));
    fr[q] = ((uint32_t)d <= 3u) ? rr : ((d == 4) ? vl : 0u);
  }
  return __builtin_bit_cast(half8, fr);
}

// -------- prep: basis + relu(x) f16 + weight B-fragments, all in ws --------
__global__ __launch_bounds__(256) void prep_all(const float* __restrict__ x,
                                                const float* __restrict__ bw,
                                                const float* __restrict__ sw,
                                                const float* __restrict__ sc,
                                                half8* __restrict__ ws) {
  int bid = blockIdx.x;
  if (bid < 2048) {
    // basis: thread handles 4 consecutive w of one (b,h,cperm) row
    int t = bid * 256 + threadIdx.x;        // 0..524287
    int w4 = t & 15;
    int cperm = (t >> 4) & 31;
    int bh = t >> 9;                        // b*64 + h
    int c = ((cperm & 7) << 2) | (cperm >> 3);   // c = 4g + quad
    const float4 v = *(const float4*)(x + (bh >> 6) * 131072 + c * 4096 +
                                      (bh & 63) * 64 + w4 * 4);
    half8* dst = ws + NBF + (size_t)t * 4;
    dst[0] = bspline8(v.x);
    dst[1] = bspline8(v.y);
    dst[2] = bspline8(v.z);
    dst[3] = bspline8(v.w);
  } else if (bid < 3072) {
    // relu(x) -> f16, channel-major: slot ((b*64+h)*64+w)*4 + quad
    int t = (bid - 2048) * 256 + threadIdx.x;    // 0..262143
    int quad = t & 3;
    int w = (t >> 2) & 63;
    int bh = t >> 8;                             // b*64 + h
    const float* xp = x + (bh >> 6) * 131072 + (quad * 8) * 4096 + (bh & 63) * 64 + w;
    half8 v;
#pragma unroll
    for (int j = 0; j < 8; ++j) v[j] = (_Float16)fmaxf(xp[j * 4096], 0.0f);
    ws[NBF + NBAS + t] = v;
  } else {
    int t = (bid - 3072) * 256 + threadIdx.x;    // 0..20735
    half8 v;
    int dst;
    if (t < NOUT * FIN) {                   // spline (o,f) pairs
      int o = t / FIN;
      int f = t - o * FIN;
      float scale = sc[t];
      const float* p = sw + t * 8;
#pragma unroll
      for (int c = 0; c < 8; ++c) v[c] = (_Float16)(p[c] * scale);
      int ch = f / 9;
      int r  = f - ch * 9;
      int ii = r / 3;
      int jj = r - ii * 3;
      int g  = ch >> 2, q = ch & 3;
      int kt = ii * 24 + jj * 8 + g;
      dst = (kt * 4 + (o >> 4)) * 64 + q * 16 + (o & 15);
    } else {                                // base frags, K-permuted
      int t2 = t - NOUT * FIN;
      int lane = t2 & 63;
      int nf = (t2 >> 6) & 3;
      int ktb = t2 >> 8;                    // 0..8
      int o = nf * 16 + (lane & 15);
      int q = lane >> 4;
      int i2 = ktb / 3;
      int j2 = ktb - 3 * i2;
#pragma unroll
      for (int c0 = 0; c0 < 8; ++c0)
        v[c0] = (_Float16)bw[o * FIN + 9 * (q * 8 + c0) + 3 * i2 + j2];
      dst = ((KSPL + ktb) * 4 + nf) * 64 + lane;
    }
    ws[dst] = v;
  }
}

// ---- main: M=64 px/wave, N=64/block, LDS-staged bf, in-pair K-split ----
// 8 waves: group 0 (wv<4) = g 0..3 of every (ii,jj) pair + base kb 0..3;
// group 1 = g 4..7 + base kb 4..8. Both groups walk the SAME pair sequence
// so the pair's 32 KB of B-fragments is staged to LDS once per block
// (double-buffered, issue-early/write-late). Group-1 partials reduced into
// group 0 via the (re-used) LDS buffer after the last pair.
__global__ __launch_bounds__(512, 2) void kan_main(
    const half8* __restrict__ ws,
    float* __restrict__ out) {
  __shared__ __align__(16) unsigned char ldsraw[65536];
  half8* lbf0 = (half8*)ldsraw;             // [2048] = 32 KB (pair buffer A)
  half8* lbf1 = (half8*)(ldsraw + 32768);   // pair buffer B
  float* red  = (float*)ldsraw;             // 16384 floats (after last pair)

  const half8* __restrict__ bfrag = ws;
  const half8* __restrict__ bas   = ws + NBF;
  const half8* __restrict__ xr    = ws + NBF + NBAS;

  const int tid = threadIdx.x;
  int bid0 = blockIdx.x;                // 0..255
  // XCD swizzle: 256 = 8*32, bijective
  int bid = (bid0 & 7) * 32 + (bid0 >> 3);
  const int b  = bid >> 4;
  const int hg = bid & 15;

  const int lane = tid & 63;
  const int wv   = tid >> 6;            // 0..7
  const int g2   = wv >> 2;             // K-group
  const int rw   = wv & 3;              // row-wave within group
  const int quad = lane >> 4;
  const int m16  = lane & 15;
  const int ho   = hg * 4 + rw;         // 0..63; >=62 computes garbage, not stored
  const int hoc  = ho < 61 ? ho : 61;
  const int glo  = g2 * 4;              // spline g range [glo, glo+4)

  f32x4 acc[4][4];
#pragma unroll
  for (int mt = 0; mt < 4; ++mt)
#pragma unroll
    for (int nf = 0; nf < 4; ++nf) acc[mt][nf] = (f32x4){0.f, 0.f, 0.f, 0.f};

  const half8* bb = bas + ((b * 64 + hoc) * 32 + quad * 8) * 64 + m16;

  // ---- prologue: stage pair 0 ----
#pragma unroll
  for (int i = 0; i < 4; ++i) {
    int idx = i * 512 + tid;
    lbf0[idx] = bfrag[idx];
  }
  __syncthreads();
  half8* bcur = lbf0;
  half8* balt = lbf1;

  // ---- spline pairs ----
  for (int pp = 0; pp < 9; ++pp) {
    // issue next pair's loads early (T14: write LDS after compute)
    half8 stg[4];
    if (pp < 8) {
      const half8* src = bfrag + (pp + 1) * 2048;
#pragma unroll
      for (int i = 0; i < 4; ++i) stg[i] = src[i * 512 + tid];
    }

    int ii = (pp * 11) >> 5;            // pp/3
    int jj = pp - 3 * ii;
    const half8* pA = bb + ii * 2048 + jj;
#pragma unroll
    for (int gg = 0; gg < 4; ++gg) {
      const int g = glo + gg;
      half8 af[4];
#pragma unroll
      for (int mt = 0; mt < 4; ++mt) af[mt] = pA[g * 64 + mt * 16];
#pragma unroll
      for (int nf = 0; nf < 4; ++nf) {
        half8 bf = bcur[g * 256 + nf * 64 + lane];
#pragma unroll
        for (int mt = 0; mt < 4; ++mt)
          acc[mt][nf] = __builtin_amdgcn_mfma_f32_16x16x32_f16(af[mt], bf, acc[mt][nf], 0, 0, 0);
      }
    }

    if (pp < 8) {
#pragma unroll
      for (int i = 0; i < 4; ++i) balt[i * 512 + tid] = stg[i];
    }
    __syncthreads();
    half8* t = bcur; bcur = balt; balt = t;
  }

  // ---- base K-slices (bf straight from global; split 4/5 across groups) ----
  const int klo = g2 ? 4 : 0;
  const int khi = g2 ? 9 : 4;
  for (int kb = klo; kb < khi; ++kb) {
    int i2 = (kb * 11) >> 5;            // kb/3
    int j2 = kb - 3 * i2;
    const half8* q = xr + ((b * 64 + hoc + i2) * 64 + m16 + j2) * 4 + quad;
    half8 af[4];
#pragma unroll
    for (int mt = 0; mt < 4; ++mt) af[mt] = q[mt * 64];
    const half8* bfp = bfrag + (KSPL + kb) * 256 + lane;
#pragma unroll
    for (int nf = 0; nf < 4; ++nf) {
      half8 bf = bfp[nf * 64];
#pragma unroll
      for (int mt = 0; mt < 4; ++mt)
        acc[mt][nf] = __builtin_amdgcn_mfma_f32_16x16x32_f16(af[mt], bf, acc[mt][nf], 0, 0, 0);
    }
  }

  // ---- K-split reduce (group 1 -> group 0) via re-used LDS ----
  // slot = (rw*64+lane)*64 floats; chunk c=(mt*4+nf) rotated by lane to cap
  // bank conflicts at 8-way (one-shot).
  if (g2) {
    int base = (rw * 64 + lane) * 64;
#pragma unroll
    for (int mt = 0; mt < 4; ++mt)
#pragma unroll
      for (int nf = 0; nf < 4; ++nf) {
        int pos = ((mt * 4 + nf) + lane) & 15;
        *(f32x4*)&red[base + pos * 4] = acc[mt][nf];
      }
  }
  __syncthreads();

  if (!g2) {
    int base = (rw * 64 + lane) * 64;
#pragma unroll
    for (int mt = 0; mt < 4; ++mt)
#pragma unroll
      for (int nf = 0; nf < 4; ++nf) {
        int pos = ((mt * 4 + nf) + lane) & 15;
        acc[mt][nf] += *(const f32x4*)&red[base + pos * 4];
      }

    // ---- epilogue: col(=out)=m16, row(=pixel)=mt*16+quad*4+rg ----
    if (ho < 62) {
      float* ob = out + b * (NOUT * LPB) + ho * 62;
#pragma unroll
      for (int mt = 0; mt < 4; ++mt) {
#pragma unroll
        for (int rg = 0; rg < 4; ++rg) {
          int wo2 = mt * 16 + quad * 4 + rg;
          if (wo2 < 62) {
#pragma unroll
            for (int nf = 0; nf < 4; ++nf) {
              int o = nf * 16 + m16;
              ob[o * LPB + wo2] = acc[mt][nf][rg];
            }
          }
        }
      }
    }
  }
}

// ================= legacy fallback (round-0 verified, verbatim) =================
__global__ void prep_bfrag_legacy(const float* __restrict__ bw,
                                  const float* __restrict__ sw,
                                  const float* __restrict__ sc,
                                  half8* __restrict__ bfrag) {
  int t = blockIdx.x * 256 + threadIdx.x;
  half8 v;
  int dst;
  if (t < NOUT * FIN) {
    int o = t / FIN;
    int f = t - o * FIN;
    float scale = sc[t];
    const float* p = sw + t * 8;
#pragma unroll
    for (int c = 0; c < 8; ++c) v[c] = (_Float16)(p[c] * scale);
    int ch = f / 9;
    int r  = f - ch * 9;
    int ii = r / 3;
    int jj = r - ii * 3;
    int g  = ch >> 2, q = ch & 3;
    int kt = ii * 24 + jj * 8 + g;
    dst = (kt * 4 + (o >> 4)) * 64 + q * 16 + (o & 15);
  } else {
    int t2 = t - NOUT * FIN;
    int lane = t2 & 63;
    int nf = (t2 >> 6) & 3;
    int ktb = t2 >> 8;
    int o = nf * 16 + (lane & 15);
    int f0 = ktb * 32 + (lane >> 4) * 8;
    const float* p = bw + o * FIN + f0;
#pragma unroll
    for (int c = 0; c < 8; ++c) v[c] = (_Float16)p[c];
    dst = ((KSPL + ktb) * 4 + nf) * 64 + lane;
  }
  bfrag[dst] = v;
}

__global__ __launch_bounds__(256, 4) void kan_main_legacy(
    const float* __restrict__ x,
    const half8* __restrict__ bfrag,
    float* __restrict__ out) {
  __shared__ float lx[LDSL];
  const int tid = threadIdx.x;
  const int bid = blockIdx.x;
  const int b  = bid / 62;
  const int ho = bid - b * 62;
  const float* xb = x + b * 131072 + ho * 64;
#pragma unroll
  for (int r = 0; r < 6; ++r) {
    int gid = r * 256 + tid;
    int row = gid >> 4;
    int c   = (row * 683) >> 11;
    int ii  = row - c * 3;
    int colv = (gid & 15) * 4;
    const float4 v = *(const float4*)(xb + c * 4096 + ii * 64 + colv);
    *(float4*)(&lx[c * SCL + ii * 64 + colv]) = v;
  }
  __syncthreads();
  const int lane = tid & 63;
  const int wv   = tid >> 6;
  const int quad = lane >> 4;
  const int m16  = lane & 15;
  const int wo   = wv * 16 + m16;
  f32x4 acc[4];
#pragma unroll
  for (int nf = 0; nf < 4; ++nf) acc[nf] = (f32x4){0.f, 0.f, 0.f, 0.f};
  int kt = 0;
#pragma unroll
  for (int ii = 0; ii < 3; ++ii) {
#pragma unroll
    for (int jj = 0; jj < 3; ++jj) {
      const float* lbase = lx + quad * SCL + ii * 64 + wo + jj;
#pragma unroll
      for (int g = 0; g < 8; ++g) {
        float xv = lbase[g * (4 * SCL)];
        half8 af = bspline8(xv);
#pragma unroll
        for (int nf = 0; nf < 4; ++nf) {
          half8 bf = bfrag[(kt * 4 + nf) * 64 + lane];
          acc[nf] = __builtin_amdgcn_mfma_f32_16x16x32_f16(af, bf, acc[nf], 0, 0, 0);
        }
        ++kt;
      }
    }
  }
#pragma unroll
  for (int kb = 0; kb < 9; ++kb) {
    int f0 = kb * 32 + quad * 8;
    half8 a;
#pragma unroll
    for (int j = 0; j < 8; ++j) {
      int f = f0 + j;
      int c = (f * 57) >> 9;
      int r = f - c * 9;
      int i2 = (r * 11) >> 5;
      int j2 = r - i2 * 3;
      a[j] = (_Float16)fmaxf(lx[c * SCL + i2 * 64 + wo + j2], 0.0f);
    }
#pragma unroll
    for (int nf = 0; nf < 4; ++nf) {
      half8 bf = bfrag[((KSPL + kb) * 4 + nf) * 64 + lane];
      acc[nf] = __builtin_amdgcn_mfma_f32_16x16x32_f16(a, bf, acc[nf], 0, 0, 0);
    }
  }
  float* ob = out + b * (NOUT * LPB) + ho * 62;
#pragma unroll
  for (int rg = 0; rg < 4; ++rg) {
    int wo2 = wv * 16 + quad * 4 + rg;
    if (wo2 < 62) {
#pragma unroll
      for (int nf = 0; nf < 4; ++nf) {
        int o = nf * 16 + m16;
        ob[o * LPB + wo2] = acc[nf][rg];
      }
    }
  }
}

extern "C" void kernel_launch(void* const* d_in, const int* in_sizes, int n_in,
                              void* d_out, int out_size, void* d_ws, size_t ws_size,
                              hipStream_t stream) {
  const float* x  = (const float*)d_in[0];
  const float* bw = (const float*)d_in[1];  // (64, 288)
  const float* sw = (const float*)d_in[2];  // (64, 288, 8)
  const float* sc = (const float*)d_in[3];  // (64, 288)
  float* out = (float*)d_out;
  half8* ws = (half8*)d_ws;

  const size_t need = (size_t)(NBF + NBAS + NXR + PADS) * sizeof(half8);  // ~38.1 MB
  if (ws_size >= need) {
    prep_all<<<3153, 256, 0, stream>>>(x, bw, sw, sc, ws);
    kan_main<<<256, 512, 0, stream>>>(ws, out);
  } else {
    prep_bfrag_legacy<<<81, 256, 0, stream>>>(bw, sw, sc, ws);
    kan_main_legacy<<<16 * 62, 256, 0, stream>>>(x, ws, out);
  }
}

// Round 7
// 119.856 us; speedup vs baseline: 1.5075x; 1.0178x over previous
//
#include <hip/hip_runtime.h>
#include <stdint.h>

typedef _Float16 half8  __attribute__((ext_vector_type(8)));
typedef float    f32x4  __attribute__((ext_vector_type(4)));
typedef float    f32x16 __attribute__((ext_vector_type(16)));
typedef uint32_t u32x4  __attribute__((ext_vector_type(4)));

#define FIN  288
#define NOUT 64
#define LPB  3844            // 62*62
#define NBF  20736           // bfrag half8 slots (331,776 B)
#define NBAS (16*64*16*64*2) // basis half8 slots (33.5 MB), [b][h][u16][w64][half2]
#define NXR  (16*64*2*64*2)  // relu(x) half8 slots (4.2 MB), [b][h][u2][w64][half2]
#define PADS 16              // OOB-read pad (w+jj overruns handled by discard)

// legacy LDS (fallback path, byte-identical to the round-0 verified kernel)
#define SCL  200
#define LDSL (31*SCL + 2*64 + 64 + 8)

// 32x32x16 MFMA layouts (A: row=l&31, k=(l>>5)*8+j; B: k=(l>>5)*8+j, col=l&31;
// C/D: col=l&31, row=(reg&3)+8*(reg>>2)+4*(l>>5), reg in [0,16)).
// Spline K per (ii,jj) pair: 16 u-slices of K=16; slice u covers channels
// c = u*2 + half, 8 spline-slots j. A-frag = ONE contiguous 1KB load from
// bas[(b,h+ii)][u][w=mt*32+(l&31)+jj][half=l>>5]  (jj additive: +2 slots).
// Base K: 9 pos x 2 u-slices; slice (pos,u) covers c = u*16+half*8+j from
// xr[(b,h+i2)][u][w+j2][half].  bf slot (spline) = pp*2048+u*128+nf*64+lane;
// (base) = 18432+(pos*2+u)*128+nf*64+lane.

// ---------------- cubic B-spline basis: 8 slots, f16-packed ----------------
__device__ inline half8 bspline8(float xv) {
  float u = fmaf(xv, 2.5f, 5.5f);
  float fi = floorf(u);
  int i = (int)fi;
  float t = u - fi, s = 1.0f - t;
  float t2 = t * t, t3 = t2 * t;
  float s2 = s * s, s3 = s2 * s;
  float w3 = t3 * 0.16666667f;
  float w0 = s3 * 0.16666667f;
  float w1 = fmaf(0.5f, t3, -t2) + 0.66666667f;
  float w2 = fmaf(0.5f, s3, -s2) + 0.66666667f;
  uint32_t u01 = __builtin_bit_cast(uint32_t, __builtin_amdgcn_cvt_pkrtz(w0, w1));
  uint32_t u23 = __builtin_bit_cast(uint32_t, __builtin_amdgcn_cvt_pkrtz(w2, w3));
  uint64_t V = (uint64_t)u01 | ((uint64_t)u23 << 32);
  uint32_t vl = (uint32_t)(V << 16);
  u32x4 fr;
#pragma unroll
  for (int q = 0; q < 4; ++q) {
    int d = i - 2 * q;
    uint32_t rr = (uint32_t)(V >> ((48 - 16 * d) & 63));
    fr[q] = ((uint32_t)d <= 3u) ? rr : ((d == 4) ? vl : 0u);
  }
  return __builtin_bit_cast(half8, fr);
}

// -------- prep: basis + relu(x) f16 + weight B-fragments, all in ws --------
__global__ __launch_bounds__(256) void prep_all(const float* __restrict__ x,
                                                const float* __restrict__ bw,
                                                const float* __restrict__ sw,
                                                const float* __restrict__ sc,
                                                half8* __restrict__ ws) {
  int bid = blockIdx.x;
  if (bid < 2048) {
    // basis: thread = 4 consecutive w of one (b,h,u,half); slot stride 2
    int t = bid * 256 + threadIdx.x;        // 0..524287
    int w4   = t & 15;
    int idx  = t >> 4;
    int half = idx & 1;
    int u    = (idx >> 1) & 15;
    int bh   = idx >> 5;                    // b*64 + h
    int c    = u * 2 + half;
    const float4 v = *(const float4*)(x + (bh >> 6) * 131072 + c * 4096 +
                                      (bh & 63) * 64 + w4 * 4);
    half8* dst = ws + NBF + ((size_t)(bh * 16 + u) * 64 + w4 * 4) * 2 + half;
    dst[0] = bspline8(v.x);
    dst[2] = bspline8(v.y);
    dst[4] = bspline8(v.z);
    dst[6] = bspline8(v.w);
  } else if (bid < 3072) {
    // relu(x) -> f16: slot ((bh*2+u)*64+w)*2 + half, half8 = ch u*16+half*8+j
    int t = (bid - 2048) * 256 + threadIdx.x;    // 0..262143
    int half = t & 1;
    int w    = (t >> 1) & 63;
    int u    = (t >> 7) & 1;
    int bh   = t >> 8;
    const float* xp = x + (bh >> 6) * 131072 + (u * 16 + half * 8) * 4096 +
                      (bh & 63) * 64 + w;
    half8 v;
#pragma unroll
    for (int j = 0; j < 8; ++j) v[j] = (_Float16)fmaxf(xp[j * 4096], 0.0f);
    ws[NBF + NBAS + ((size_t)(bh * 2 + u) * 64 + w) * 2 + half] = v;
  } else {
    int t = (bid - 3072) * 256 + threadIdx.x;    // 0..20735
    half8 v;
    int dst;
    if (t < NOUT * FIN) {                   // spline (o,f) pairs
      int o = t / FIN;
      int f = t - o * FIN;
      float scale = sc[t];
      const float* p = sw + t * 8;
#pragma unroll
      for (int j = 0; j < 8; ++j) v[j] = (_Float16)(p[j] * scale);
      int c  = f / 9;
      int r  = f - c * 9;
      int ii = r / 3;
      int jj = r - ii * 3;
      int pp = ii * 3 + jj;
      int u  = c >> 1, half = c & 1;
      int nf = o >> 5, col = o & 31;
      dst = pp * 2048 + u * 128 + nf * 64 + half * 32 + col;
    } else {                                // base frags: dst = 18432 + t2
      int t2 = t - NOUT * FIN;              // 0..2303
      int lane = t2 & 63;
      int nf   = (t2 >> 6) & 1;
      int u    = (t2 >> 7) & 1;
      int pos  = t2 >> 8;                   // 0..8
      int half = lane >> 5, col = lane & 31;
      int o = nf * 32 + col;
#pragma unroll
      for (int j = 0; j < 8; ++j)
        v[j] = (_Float16)bw[o * FIN + 9 * (u * 16 + half * 8 + j) + pos];
      dst = NOUT * FIN + t2;
    }
    ws[dst] = v;
  }
}

// ---- main: 32x32x16 MFMA, M=64 px/wave, N=64/block, LDS-staged bf ----
// 8 waves: 4 rw-rows x 2 K-groups (group g2: spline u in [g2*8, g2*8+8),
// base u = g2). Same pair-loop/dbuf/reduce skeleton as the verified R6 kernel.
__global__ __launch_bounds__(512, 2) void kan_main(
    const half8* __restrict__ ws,
    float* __restrict__ out) {
  __shared__ __align__(16) unsigned char ldsraw[65536];
  half8* lbf0 = (half8*)ldsraw;             // [2048] = 32 KB (pair buffer A)
  half8* lbf1 = (half8*)(ldsraw + 32768);   // pair buffer B
  float* red  = (float*)ldsraw;             // 16384 floats (after last pair)

  const half8* __restrict__ bfrag = ws;
  const half8* __restrict__ bas   = ws + NBF;
  const half8* __restrict__ xr    = ws + NBF + NBAS;

  const int tid = threadIdx.x;
  int bid0 = blockIdx.x;                // 0..255
  // XCD swizzle: 256 = 8*32, bijective
  int bid = (bid0 & 7) * 32 + (bid0 >> 3);
  const int b  = bid >> 4;
  const int hg = bid & 15;

  const int lane = tid & 63;
  const int wv   = tid >> 6;            // 0..7
  const int g2   = wv >> 2;             // K-group
  const int rw   = wv & 3;              // row-wave within group
  const int l31  = lane & 31;
  const int lhi  = lane >> 5;
  const int laneoff = l31 * 2 + lhi;    // af lane permutation (1KB contiguous)
  const int ho   = hg * 4 + rw;         // 0..63; >=62 computes garbage, not stored
  const int hoc  = ho < 61 ? ho : 61;
  const int ulo  = g2 * 8;              // spline u range [ulo, ulo+8)

  f32x16 acc[2][2];
#pragma unroll
  for (int mt = 0; mt < 2; ++mt)
#pragma unroll
    for (int nf = 0; nf < 2; ++nf)
#pragma unroll
      for (int e = 0; e < 16; ++e) acc[mt][nf][e] = 0.f;

  const half8* bbS = bas + (size_t)(b * 64 + hoc) * 2048 + laneoff;

  // ---- prologue: stage pair 0 ----
#pragma unroll
  for (int i = 0; i < 4; ++i) {
    int idx = i * 512 + tid;
    lbf0[idx] = bfrag[idx];
  }
  __syncthreads();
  half8* bcur = lbf0;
  half8* balt = lbf1;

  // ---- spline pairs ----
  for (int pp = 0; pp < 9; ++pp) {
    // issue next pair's loads early (write LDS after compute)
    half8 stg[4];
    if (pp < 8) {
      const half8* src = bfrag + (pp + 1) * 2048;
#pragma unroll
      for (int i = 0; i < 4; ++i) stg[i] = src[i * 512 + tid];
    }

    int ii = (pp * 11) >> 5;            // pp/3
    int jj = pp - 3 * ii;
    const half8* pAf = bbS + ii * 2048 + jj * 2;
#pragma unroll
    for (int uu = 0; uu < 8; ++uu) {
      const int u = ulo + uu;
      half8 af0 = pAf[u * 128];
      half8 af1 = pAf[u * 128 + 64];
#pragma unroll
      for (int nf = 0; nf < 2; ++nf) {
        half8 bf = bcur[u * 128 + nf * 64 + lane];
        acc[0][nf] = __builtin_amdgcn_mfma_f32_32x32x16_f16(af0, bf, acc[0][nf], 0, 0, 0);
        acc[1][nf] = __builtin_amdgcn_mfma_f32_32x32x16_f16(af1, bf, acc[1][nf], 0, 0, 0);
      }
    }

    if (pp < 8) {
#pragma unroll
      for (int i = 0; i < 4; ++i) balt[i * 512 + tid] = stg[i];
    }
    __syncthreads();
    half8* t = bcur; bcur = balt; balt = t;
  }

  // ---- base K-slices: u = g2; bf straight from global (18 KB total) ----
  for (int pos = 0; pos < 9; ++pos) {
    int i2 = (pos * 11) >> 5;           // pos/3
    int j2 = pos - 3 * i2;
    const half8* pAf = xr + (size_t)((b * 64 + hoc + i2) * 2 + g2) * 128 +
                       j2 * 2 + laneoff;
    half8 af0 = pAf[0];
    half8 af1 = pAf[64];
    const half8* bfp = bfrag + NOUT * FIN + (pos * 2 + g2) * 128 + lane;
#pragma unroll
    for (int nf = 0; nf < 2; ++nf) {
      half8 bf = bfp[nf * 64];
      acc[0][nf] = __builtin_amdgcn_mfma_f32_32x32x16_f16(af0, bf, acc[0][nf], 0, 0, 0);
      acc[1][nf] = __builtin_amdgcn_mfma_f32_32x32x16_f16(af1, bf, acc[1][nf], 0, 0, 0);
    }
  }

  // ---- K-split reduce (group 1 -> group 0) via re-used LDS ----
  if (g2) {
    int base = (rw * 64 + lane) * 64;
#pragma unroll
    for (int mt = 0; mt < 2; ++mt)
#pragma unroll
      for (int nf = 0; nf < 2; ++nf)
#pragma unroll
        for (int q4 = 0; q4 < 4; ++q4) {
          int pos = ((mt * 8 + nf * 4 + q4) + lane) & 15;
          f32x4 ch = {acc[mt][nf][q4 * 4], acc[mt][nf][q4 * 4 + 1],
                      acc[mt][nf][q4 * 4 + 2], acc[mt][nf][q4 * 4 + 3]};
          *(f32x4*)&red[base + pos * 4] = ch;
        }
  }
  __syncthreads();

  if (!g2) {
    int base = (rw * 64 + lane) * 64;
#pragma unroll
    for (int mt = 0; mt < 2; ++mt)
#pragma unroll
      for (int nf = 0; nf < 2; ++nf)
#pragma unroll
        for (int q4 = 0; q4 < 4; ++q4) {
          int pos = ((mt * 8 + nf * 4 + q4) + lane) & 15;
          f32x4 ch = *(const f32x4*)&red[base + pos * 4];
          acc[mt][nf][q4 * 4]     += ch[0];
          acc[mt][nf][q4 * 4 + 1] += ch[1];
          acc[mt][nf][q4 * 4 + 2] += ch[2];
          acc[mt][nf][q4 * 4 + 3] += ch[3];
        }

    // ---- epilogue: col(=out)=nf*32+l31, row(=px w)=mt*32+(reg&3)+8*(reg>>2)+4*lhi
    if (ho < 62) {
      float* ob = out + b * (NOUT * LPB) + ho * 62;
#pragma unroll
      for (int mt = 0; mt < 2; ++mt) {
#pragma unroll
        for (int reg = 0; reg < 16; ++reg) {
          int wo2 = mt * 32 + (reg & 3) + 8 * (reg >> 2) + 4 * lhi;
          if (wo2 < 62) {
#pragma unroll
            for (int nf = 0; nf < 2; ++nf) {
              int o = nf * 32 + l31;
              ob[o * LPB + wo2] = acc[mt][nf][reg];
            }
          }
        }
      }
    }
  }
}

// ================= legacy fallback (round-0 verified, verbatim) =================
#define KSPL 72
__global__ void prep_bfrag_legacy(const float* __restrict__ bw,
                                  const float* __restrict__ sw,
                                  const float* __restrict__ sc,
                                  half8* __restrict__ bfrag) {
  int t = blockIdx.x * 256 + threadIdx.x;
  half8 v;
  int dst;
  if (t < NOUT * FIN) {
    int o = t / FIN;
    int f = t - o * FIN;
    float scale = sc[t];
    const float* p = sw + t * 8;
#pragma unroll
    for (int c = 0; c < 8; ++c) v[c] = (_Float16)(p[c] * scale);
    int ch = f / 9;
    int r  = f - ch * 9;
    int ii = r / 3;
    int jj = r - ii * 3;
    int g  = ch >> 2, q = ch & 3;
    int kt = ii * 24 + jj * 8 + g;
    dst = (kt * 4 + (o >> 4)) * 64 + q * 16 + (o & 15);
  } else {
    int t2 = t - NOUT * FIN;
    int lane = t2 & 63;
    int nf = (t2 >> 6) & 3;
    int ktb = t2 >> 8;
    int o = nf * 16 + (lane & 15);
    int f0 = ktb * 32 + (lane >> 4) * 8;
    const float* p = bw + o * FIN + f0;
#pragma unroll
    for (int c = 0; c < 8; ++c) v[c] = (_Float16)p[c];
    dst = ((KSPL + ktb) * 4 + nf) * 64 + lane;
  }
  bfrag[dst] = v;
}

__global__ __launch_bounds__(256, 4) void kan_main_legacy(
    const float* __restrict__ x,
    const half8* __restrict__ bfrag,
    float* __restrict__ out) {
  __shared__ float lx[LDSL];
  const int tid = threadIdx.x;
  const int bid = blockIdx.x;
  const int b  = bid / 62;
  const int ho = bid - b * 62;
  const float* xb = x + b * 131072 + ho * 64;
#pragma unroll
  for (int r = 0; r < 6; ++r) {
    int gid = r * 256 + tid;
    int row = gid >> 4;
    int c   = (row * 683) >> 11;
    int ii  = row - c * 3;
    int colv = (gid & 15) * 4;
    const float4 v = *(const float4*)(xb + c * 4096 + ii * 64 + colv);
    *(float4*)(&lx[c * SCL + ii * 64 + colv]) = v;
  }
  __syncthreads();
  const int lane = tid & 63;
  const int wv   = tid >> 6;
  const int quad = lane >> 4;
  const int m16  = lane & 15;
  const int wo   = wv * 16 + m16;
  f32x4 acc[4];
#pragma unroll
  for (int nf = 0; nf < 4; ++nf) acc[nf] = (f32x4){0.f, 0.f, 0.f, 0.f};
  int kt = 0;
#pragma unroll
  for (int ii = 0; ii < 3; ++ii) {
#pragma unroll
    for (int jj = 0; jj < 3; ++jj) {
      const float* lbase = lx + quad * SCL + ii * 64 + wo + jj;
#pragma unroll
      for (int g = 0; g < 8; ++g) {
        float xv = lbase[g * (4 * SCL)];
        half8 af = bspline8(xv);
#pragma unroll
        for (int nf = 0; nf < 4; ++nf) {
          half8 bf = bfrag[(kt * 4 + nf) * 64 + lane];
          acc[nf] = __builtin_amdgcn_mfma_f32_16x16x32_f16(af, bf, acc[nf], 0, 0, 0);
        }
        ++kt;
      }
    }
  }
#pragma unroll
  for (int kb = 0; kb < 9; ++kb) {
    int f0 = kb * 32 + quad * 8;
    half8 a;
#pragma unroll
    for (int j = 0; j < 8; ++j) {
      int f = f0 + j;
      int c = (f * 57) >> 9;
      int r = f - c * 9;
      int i2 = (r * 11) >> 5;
      int j2 = r - i2 * 3;
      a[j] = (_Float16)fmaxf(lx[c * SCL + i2 * 64 + wo + j2], 0.0f);
    }
#pragma unroll
    for (int nf = 0; nf < 4; ++nf) {
      half8 bf = bfrag[((KSPL + kb) * 4 + nf) * 64 + lane];
      acc[nf] = __builtin_amdgcn_mfma_f32_16x16x32_f16(a, bf, acc[nf], 0, 0, 0);
    }
  }
  float* ob = out + b * (NOUT * LPB) + ho * 62;
#pragma unroll
  for (int rg = 0; rg < 4; ++rg) {
    int wo2 = wv * 16 + quad * 4 + rg;
    if (wo2 < 62) {
#pragma unroll
      for (int nf = 0; nf < 4; ++nf) {
        int o = nf * 16 + m16;
        ob[o * LPB + wo2] = acc[nf][rg];
      }
    }
  }
}

extern "C" void kernel_launch(void* const* d_in, const int* in_sizes, int n_in,
                              void* d_out, int out_size, void* d_ws, size_t ws_size,
                              hipStream_t stream) {
  const float* x  = (const float*)d_in[0];
  const float* bw = (const float*)d_in[1];  // (64, 288)
  const float* sw = (const float*)d_in[2];  // (64, 288, 8)
  const float* sc = (const float*)d_in[3];  // (64, 288)
  float* out = (float*)d_out;
  half8* ws = (half8*)d_ws;

  const size_t need = (size_t)(NBF + NBAS + NXR + PADS) * sizeof(half8);  // ~38.1 MB
  if (ws_size >= need) {
    prep_all<<<3153, 256, 0, stream>>>(x, bw, sw, sc, ws);
    kan_main<<<256, 512, 0, stream>>>(ws, out);
  } else {
    prep_bfrag_legacy<<<81, 256, 0, stream>>>(bw, sw, sc, ws);
    kan_main_legacy<<<16 * 62, 256, 0, stream>>>(x, ws, out);
  }
}

// Round 8
// 117.493 us; speedup vs baseline: 1.5378x; 1.0201x over previous
//
#include <hip/hip_runtime.h>
#include <stdint.h>

typedef _Float16 half8  __attribute__((ext_vector_type(8)));
typedef float    f32x4  __attribute__((ext_vector_type(4)));
typedef float    f32x16 __attribute__((ext_vector_type(16)));
typedef uint32_t u32x4  __attribute__((ext_vector_type(4)));

#define FIN  288
#define NOUT 64
#define LPB  3844            // 62*62
#define NBF  20736           // bfrag half8 slots (331,776 B)
#define NBAS (16*64*16*64*2) // basis half8 slots (33.5 MB), [b][h][u16][w64][half2]
#define NXR  (16*64*2*64*2)  // relu(x) half8 slots (4.2 MB), [b][h][u2][w64][half2]
#define PADS 16              // OOB-read pad

// legacy LDS (fallback path, byte-identical to the round-0 verified kernel)
#define SCL  200
#define LDSL (31*SCL + 2*64 + 64 + 8)

// 32x32x16 MFMA layouts (A: row=l&31, k=(l>>5)*8+j; B: k=(l>>5)*8+j, col=l&31;
// C/D: col=l&31, row=(reg&3)+8*(reg>>2)+4*(l>>5)).  Same mappings as the
// round-7 verified kernel; this round only changes SCHEDULING (af prefetch
// one full pair ahead in registers) + prep store coalescing.

// ---------------- cubic B-spline basis: 8 slots, f16-packed ----------------
__device__ inline half8 bspline8(float xv) {
  float u = fmaf(xv, 2.5f, 5.5f);
  float fi = floorf(u);
  int i = (int)fi;
  float t = u - fi, s = 1.0f - t;
  float t2 = t * t, t3 = t2 * t;
  float s2 = s * s, s3 = s2 * s;
  float w3 = t3 * 0.16666667f;
  float w0 = s3 * 0.16666667f;
  float w1 = fmaf(0.5f, t3, -t2) + 0.66666667f;
  float w2 = fmaf(0.5f, s3, -s2) + 0.66666667f;
  uint32_t u01 = __builtin_bit_cast(uint32_t, __builtin_amdgcn_cvt_pkrtz(w0, w1));
  uint32_t u23 = __builtin_bit_cast(uint32_t, __builtin_amdgcn_cvt_pkrtz(w2, w3));
  uint64_t V = (uint64_t)u01 | ((uint64_t)u23 << 32);
  uint32_t vl = (uint32_t)(V << 16);
  u32x4 fr;
#pragma unroll
  for (int q = 0; q < 4; ++q) {
    int d = i - 2 * q;
    uint32_t rr = (uint32_t)(V >> ((48 - 16 * d) & 63));
    fr[q] = ((uint32_t)d <= 3u) ? rr : ((d == 4) ? vl : 0u);
  }
  return __builtin_bit_cast(half8, fr);
}

// -------- prep: basis + relu(x) f16 + weight B-fragments, all in ws --------
__global__ __launch_bounds__(256) void prep_all(const float* __restrict__ x,
                                                const float* __restrict__ bw,
                                                const float* __restrict__ sw,
                                                const float* __restrict__ sc,
                                                half8* __restrict__ ws) {
  int bid = blockIdx.x;
  if (bid < 8192) {
    // basis: thread t writes slot t (perfectly coalesced 1KB/wave stores)
    int t = bid * 256 + threadIdx.x;        // 0..2097151
    int half = t & 1;
    int w    = (t >> 1) & 63;
    int u    = (t >> 7) & 15;
    int bh   = t >> 11;                     // b*64 + h
    float xv = x[(size_t)(bh >> 6) * 131072 + (u * 2 + half) * 4096 +
                 (bh & 63) * 64 + w];
    ws[NBF + t] = bspline8(xv);
  } else if (bid < 9216) {
    // relu(x) -> f16: slot ((bh*2+u)*64+w)*2 + half, half8 = ch u*16+half*8+j
    int t = (bid - 8192) * 256 + threadIdx.x;    // 0..262143
    int half = t & 1;
    int w    = (t >> 1) & 63;
    int u    = (t >> 7) & 1;
    int bh   = t >> 8;
    const float* xp = x + (size_t)(bh >> 6) * 131072 + (u * 16 + half * 8) * 4096 +
                      (bh & 63) * 64 + w;
    half8 v;
#pragma unroll
    for (int j = 0; j < 8; ++j) v[j] = (_Float16)fmaxf(xp[j * 4096], 0.0f);
    ws[NBF + NBAS + t] = v;
  } else {
    int t = (bid - 9216) * 256 + threadIdx.x;    // 0..20735
    half8 v;
    int dst;
    if (t < NOUT * FIN) {                   // spline (o,f) pairs
      int o = t / FIN;
      int f = t - o * FIN;
      float scale = sc[t];
      const float* p = sw + t * 8;
#pragma unroll
      for (int j = 0; j < 8; ++j) v[j] = (_Float16)(p[j] * scale);
      int c  = f / 9;
      int r  = f - c * 9;
      int ii = r / 3;
      int jj = r - ii * 3;
      int pp = ii * 3 + jj;
      int u  = c >> 1, half = c & 1;
      int nf = o >> 5, col = o & 31;
      dst = pp * 2048 + u * 128 + nf * 64 + half * 32 + col;
    } else {                                // base frags: dst = 18432 + t2
      int t2 = t - NOUT * FIN;              // 0..2303
      int lane = t2 & 63;
      int nf   = (t2 >> 6) & 1;
      int u    = (t2 >> 7) & 1;
      int pos  = t2 >> 8;                   // 0..8
      int half = lane >> 5, col = lane & 31;
      int o = nf * 32 + col;
#pragma unroll
      for (int j = 0; j < 8; ++j)
        v[j] = (_Float16)bw[o * FIN + 9 * (u * 16 + half * 8 + j) + pos];
      dst = NOUT * FIN + t2;
    }
    ws[dst] = v;
  }
}

// ---- main: 32x32x16, M=64 px/wave, N=64/block, LDS bf dbuf + REG af dbuf ----
#define MFMA32(A, B, C) __builtin_amdgcn_mfma_f32_32x32x16_f16((A), (B), (C), 0, 0, 0)

// load the 16 af fragments of spline pair PP into AF (issue-early)
#define LOAD_AF(PP, AF)                                                     \
  {                                                                         \
    const half8* pAf_ = bbS + ((PP) / 3) * 2048 + ((PP) % 3) * 2;           \
    _Pragma("unroll")                                                       \
    for (int uu = 0; uu < 8; ++uu) {                                        \
      AF[uu * 2]     = pAf_[(ulo + uu) * 128];                              \
      AF[uu * 2 + 1] = pAf_[(ulo + uu) * 128 + 64];                         \
    }                                                                       \
  }

// one spline pair: stage next bf (reg), prefetch next af, compute current
#define PAIR(PP, AFC, AFN)                                                  \
  {                                                                         \
    half8 stg[4];                                                           \
    if ((PP) < 8) {                                                         \
      const half8* src_ = bfrag + ((PP) + 1) * 2048;                        \
      _Pragma("unroll")                                                     \
      for (int i = 0; i < 4; ++i) stg[i] = src_[i * 512 + tid];             \
      LOAD_AF((PP) + 1, AFN)                                                \
    }                                                                       \
    _Pragma("unroll")                                                       \
    for (int uu = 0; uu < 8; ++uu) {                                        \
      int u_ = ulo + uu;                                                    \
      _Pragma("unroll")                                                     \
      for (int nf = 0; nf < 2; ++nf) {                                      \
        half8 bf_ = bcur[u_ * 128 + nf * 64 + lane];                        \
        acc[0][nf] = MFMA32(AFC[uu * 2], bf_, acc[0][nf]);                  \
        acc[1][nf] = MFMA32(AFC[uu * 2 + 1], bf_, acc[1][nf]);              \
      }                                                                     \
    }                                                                       \
    if ((PP) < 8) {                                                         \
      _Pragma("unroll")                                                     \
      for (int i = 0; i < 4; ++i) balt[i * 512 + tid] = stg[i];             \
    }                                                                       \
    __syncthreads();                                                        \
    { half8* t_ = bcur; bcur = balt; balt = t_; }                           \
  }

#define BASE_LOAD(POS, A0, A1, B0, B1)                                      \
  {                                                                         \
    constexpr int i2_ = (POS) / 3, j2_ = (POS) - 3 * ((POS) / 3);           \
    const half8* pAf_ = xr + (size_t)((b * 64 + hoc + i2_) * 2 + g2) * 128 + \
                        j2_ * 2 + laneoff;                                  \
    A0 = pAf_[0];                                                           \
    A1 = pAf_[64];                                                          \
    const half8* bfp_ = bfrag + NOUT * FIN + ((POS) * 2 + g2) * 128 + lane; \
    B0 = bfp_[0];                                                           \
    B1 = bfp_[64];                                                          \
  }

#define BASE_MMA(A0, A1, B0, B1)                                            \
  {                                                                         \
    acc[0][0] = MFMA32(A0, B0, acc[0][0]);                                  \
    acc[1][0] = MFMA32(A1, B0, acc[1][0]);                                  \
    acc[0][1] = MFMA32(A0, B1, acc[0][1]);                                  \
    acc[1][1] = MFMA32(A1, B1, acc[1][1]);                                  \
  }

__global__ __launch_bounds__(512, 2) void kan_main(
    const half8* __restrict__ ws,
    float* __restrict__ out) {
  __shared__ __align__(16) unsigned char ldsraw[65536];
  half8* lbf0 = (half8*)ldsraw;             // [2048] = 32 KB (pair buffer A)
  half8* lbf1 = (half8*)(ldsraw + 32768);   // pair buffer B
  float* red  = (float*)ldsraw;             // 16384 floats (after last pair)

  const half8* __restrict__ bfrag = ws;
  const half8* __restrict__ bas   = ws + NBF;
  const half8* __restrict__ xr    = ws + NBF + NBAS;

  const int tid = threadIdx.x;
  int bid0 = blockIdx.x;                // 0..255
  // XCD swizzle: 256 = 8*32, bijective
  int bid = (bid0 & 7) * 32 + (bid0 >> 3);
  const int b  = bid >> 4;
  const int hg = bid & 15;

  const int lane = tid & 63;
  const int wv   = tid >> 6;            // 0..7
  const int g2   = wv >> 2;             // K-group
  const int rw   = wv & 3;              // row-wave within group
  const int l31  = lane & 31;
  const int lhi  = lane >> 5;
  const int laneoff = l31 * 2 + lhi;    // af lane permutation (1KB contiguous)
  const int ho   = hg * 4 + rw;         // 0..63; >=62 computes garbage, not stored
  const int hoc  = ho < 61 ? ho : 61;
  const int ulo  = g2 * 8;              // spline u range [ulo, ulo+8)

  f32x16 acc[2][2];
#pragma unroll
  for (int mt = 0; mt < 2; ++mt)
#pragma unroll
    for (int nf = 0; nf < 2; ++nf)
#pragma unroll
      for (int e = 0; e < 16; ++e) acc[mt][nf][e] = 0.f;

  const half8* bbS = bas + (size_t)(b * 64 + hoc) * 2048 + laneoff;

  half8 afA[16], afB[16];

  // ---- prologue: stage pair 0 bf + load pair 0 af ----
#pragma unroll
  for (int i = 0; i < 4; ++i) {
    int idx = i * 512 + tid;
    lbf0[idx] = bfrag[idx];
  }
  LOAD_AF(0, afA)
  __syncthreads();
  half8* bcur = lbf0;
  half8* balt = lbf1;

  half8 bx0, bx1, bxb0, bxb1;           // base prefetch set X
  half8 by0, by1, byb0, byb1;           // base prefetch set Y

  // ---- spline pairs, fully unrolled with alternating af register sets ----
  PAIR(0, afA, afB)
  PAIR(1, afB, afA)
  PAIR(2, afA, afB)
  PAIR(3, afB, afA)
  PAIR(4, afA, afB)
  PAIR(5, afB, afA)
  PAIR(6, afA, afB)
  PAIR(7, afB, afA)
  BASE_LOAD(0, bx0, bx1, bxb0, bxb1)    // overlap base pos-0 loads w/ last pair
  PAIR(8, afA, afB)

  // ---- base K-slices: 1-ahead prefetch, alternating X/Y sets ----
  BASE_LOAD(1, by0, by1, byb0, byb1)
  BASE_MMA(bx0, bx1, bxb0, bxb1)
  BASE_LOAD(2, bx0, bx1, bxb0, bxb1)
  BASE_MMA(by0, by1, byb0, byb1)
  BASE_LOAD(3, by0, by1, byb0, byb1)
  BASE_MMA(bx0, bx1, bxb0, bxb1)
  BASE_LOAD(4, bx0, bx1, bxb0, bxb1)
  BASE_MMA(by0, by1, byb0, byb1)
  BASE_LOAD(5, by0, by1, byb0, byb1)
  BASE_MMA(bx0, bx1, bxb0, bxb1)
  BASE_LOAD(6, bx0, bx1, bxb0, bxb1)
  BASE_MMA(by0, by1, byb0, byb1)
  BASE_LOAD(7, by0, by1, byb0, byb1)
  BASE_MMA(bx0, bx1, bxb0, bxb1)
  BASE_LOAD(8, bx0, bx1, bxb0, bxb1)
  BASE_MMA(by0, by1, byb0, byb1)
  BASE_MMA(bx0, bx1, bxb0, bxb1)

  // ---- K-split reduce (group 1 -> group 0) via re-used LDS ----
  if (g2) {
    int base = (rw * 64 + lane) * 64;
#pragma unroll
    for (int mt = 0; mt < 2; ++mt)
#pragma unroll
      for (int nf = 0; nf < 2; ++nf)
#pragma unroll
        for (int q4 = 0; q4 < 4; ++q4) {
          int pos = ((mt * 8 + nf * 4 + q4) + lane) & 15;
          f32x4 ch = {acc[mt][nf][q4 * 4], acc[mt][nf][q4 * 4 + 1],
                      acc[mt][nf][q4 * 4 + 2], acc[mt][nf][q4 * 4 + 3]};
          *(f32x4*)&red[base + pos * 4] = ch;
        }
  }
  __syncthreads();

  if (!g2) {
    int base = (rw * 64 + lane) * 64;
#pragma unroll
    for (int mt = 0; mt < 2; ++mt)
#pragma unroll
      for (int nf = 0; nf < 2; ++nf)
#pragma unroll
        for (int q4 = 0; q4 < 4; ++q4) {
          int pos = ((mt * 8 + nf * 4 + q4) + lane) & 15;
          f32x4 ch = *(const f32x4*)&red[base + pos * 4];
          acc[mt][nf][q4 * 4]     += ch[0];
          acc[mt][nf][q4 * 4 + 1] += ch[1];
          acc[mt][nf][q4 * 4 + 2] += ch[2];
          acc[mt][nf][q4 * 4 + 3] += ch[3];
        }

    // ---- epilogue: col(=out)=nf*32+l31, row(=px w)=mt*32+(reg&3)+8*(reg>>2)+4*lhi
    if (ho < 62) {
      float* ob = out + b * (NOUT * LPB) + ho * 62;
#pragma unroll
      for (int mt = 0; mt < 2; ++mt) {
#pragma unroll
        for (int reg = 0; reg < 16; ++reg) {
          int wo2 = mt * 32 + (reg & 3) + 8 * (reg >> 2) + 4 * lhi;
          if (wo2 < 62) {
#pragma unroll
            for (int nf = 0; nf < 2; ++nf) {
              int o = nf * 32 + l31;
              ob[o * LPB + wo2] = acc[mt][nf][reg];
            }
          }
        }
      }
    }
  }
}

// ================= legacy fallback (round-0 verified, verbatim) =================
#define KSPL 72
__global__ void prep_bfrag_legacy(const float* __restrict__ bw,
                                  const float* __restrict__ sw,
                                  const float* __restrict__ sc,
                                  half8* __restrict__ bfrag) {
  int t = blockIdx.x * 256 + threadIdx.x;
  half8 v;
  int dst;
  if (t < NOUT * FIN) {
    int o = t / FIN;
    int f = t - o * FIN;
    float scale = sc[t];
    const float* p = sw + t * 8;
#pragma unroll
    for (int c = 0; c < 8; ++c) v[c] = (_Float16)(p[c] * scale);
    int ch = f / 9;
    int r  = f - ch * 9;
    int ii = r / 3;
    int jj = r - ii * 3;
    int g  = ch >> 2, q = ch & 3;
    int kt = ii * 24 + jj * 8 + g;
    dst = (kt * 4 + (o >> 4)) * 64 + q * 16 + (o & 15);
  } else {
    int t2 = t - NOUT * FIN;
    int lane = t2 & 63;
    int nf = (t2 >> 6) & 3;
    int ktb = t2 >> 8;
    int o = nf * 16 + (lane & 15);
    int f0 = ktb * 32 + (lane >> 4) * 8;
    const float* p = bw + o * FIN + f0;
#pragma unroll
    for (int c = 0; c < 8; ++c) v[c] = (_Float16)p[c];
    dst = ((KSPL + ktb) * 4 + nf) * 64 + lane;
  }
  bfrag[dst] = v;
}

__global__ __launch_bounds__(256, 4) void kan_main_legacy(
    const float* __restrict__ x,
    const half8* __restrict__ bfrag,
    float* __restrict__ out) {
  __shared__ float lx[LDSL];
  const int tid = threadIdx.x;
  const int bid = blockIdx.x;
  const int b  = bid / 62;
  const int ho = bid - b * 62;
  const float* xb = x + b * 131072 + ho * 64;
#pragma unroll
  for (int r = 0; r < 6; ++r) {
    int gid = r * 256 + tid;
    int row = gid >> 4;
    int c   = (row * 683) >> 11;
    int ii  = row - c * 3;
    int colv = (gid & 15) * 4;
    const float4 v = *(const float4*)(xb + c * 4096 + ii * 64 + colv);
    *(float4*)(&lx[c * SCL + ii * 64 + colv]) = v;
  }
  __syncthreads();
  const int lane = tid & 63;
  const int wv   = tid >> 6;
  const int quad = lane >> 4;
  const int m16  = lane & 15;
  const int wo   = wv * 16 + m16;
  f32x4 acc[4];
#pragma unroll
  for (int nf = 0; nf < 4; ++nf) acc[nf] = (f32x4){0.f, 0.f, 0.f, 0.f};
  int kt = 0;
#pragma unroll
  for (int ii = 0; ii < 3; ++ii) {
#pragma unroll
    for (int jj = 0; jj < 3; ++jj) {
      const float* lbase = lx + quad * SCL + ii * 64 + wo + jj;
#pragma unroll
      for (int g = 0; g < 8; ++g) {
        float xv = lbase[g * (4 * SCL)];
        half8 af = bspline8(xv);
#pragma unroll
        for (int nf = 0; nf < 4; ++nf) {
          half8 bf = bfrag[(kt * 4 + nf) * 64 + lane];
          acc[nf] = __builtin_amdgcn_mfma_f32_16x16x32_f16(af, bf, acc[nf], 0, 0, 0);
        }
        ++kt;
      }
    }
  }
#pragma unroll
  for (int kb = 0; kb < 9; ++kb) {
    int f0 = kb * 32 + quad * 8;
    half8 a;
#pragma unroll
    for (int j = 0; j < 8; ++j) {
      int f = f0 + j;
      int c = (f * 57) >> 9;
      int r = f - c * 9;
      int i2 = (r * 11) >> 5;
      int j2 = r - i2 * 3;
      a[j] = (_Float16)fmaxf(lx[c * SCL + i2 * 64 + wo + j2], 0.0f);
    }
#pragma unroll
    for (int nf = 0; nf < 4; ++nf) {
      half8 bf = bfrag[((KSPL + kb) * 4 + nf) * 64 + lane];
      acc[nf] = __builtin_amdgcn_mfma_f32_16x16x32_f16(a, bf, acc[nf], 0, 0, 0);
    }
  }
  float* ob = out + b * (NOUT * LPB) + ho * 62;
#pragma unroll
  for (int rg = 0; rg < 4; ++rg) {
    int wo2 = wv * 16 + quad * 4 + rg;
    if (wo2 < 62) {
#pragma unroll
      for (int nf = 0; nf < 4; ++nf) {
        int o = nf * 16 + m16;
        ob[o * LPB + wo2] = acc[nf][rg];
      }
    }
  }
}

extern "C" void kernel_launch(void* const* d_in, const int* in_sizes, int n_in,
                              void* d_out, int out_size, void* d_ws, size_t ws_size,
                              hipStream_t stream) {
  const float* x  = (const float*)d_in[0];
  const float* bw = (const float*)d_in[1];  // (64, 288)
  const float* sw = (const float*)d_in[2];  // (64, 288, 8)
  const float* sc = (const float*)d_in[3];  // (64, 288)
  float* out = (float*)d_out;
  half8* ws = (half8*)d_ws;

  const size_t need = (size_t)(NBF + NBAS + NXR + PADS) * sizeof(half8);  // ~38.1 MB
  if (ws_size >= need) {
    prep_all<<<9297, 256, 0, stream>>>(x, bw, sw, sc, ws);
    kan_main<<<256, 512, 0, stream>>>(ws, out);
  } else {
    prep_bfrag_legacy<<<81, 256, 0, stream>>>(bw, sw, sc, ws);
    kan_main_legacy<<<16 * 62, 256, 0, stream>>>(x, ws, out);
  }
}